// Round 7
// baseline (532.875 us; speedup 1.0000x reference)
//
#include <hip/hip_runtime.h>

typedef unsigned short u16;
typedef unsigned int u32;
typedef __attribute__((ext_vector_type(8))) short short8;
typedef __attribute__((ext_vector_type(4))) float f32x4;

#define NN 50000
#define EE 800000
#define EPAD (EE + 8*NN)   // max padded edges = 1,200,000

__device__ __forceinline__ float b2f(u16 u){ union{float f;u32 i;}x; x.i=((u32)u)<<16; return x.f; }
__device__ __forceinline__ u16 f2b(float f){ union{float f;u32 i;}x; x.f=f; u32 i=x.i; return (u16)((i + 0x7fffu + ((i>>16)&1u))>>16); }
__device__ __forceinline__ float pexp(float sc){ sc = sc>=0.f ? sc : 0.2f*sc; return __expf(fminf(sc,60.f)); }

// ---------- converts ----------
__global__ void k_f2b4(const float* __restrict__ x, u16* __restrict__ y, int n4){
  int i = blockIdx.x*256 + threadIdx.x;
  if (i >= n4) return;
  float4 v = ((const float4*)x)[i];
  ushort4 o; o.x=f2b(v.x); o.y=f2b(v.y); o.z=f2b(v.z); o.w=f2b(v.w);
  ((ushort4*)y)[i]=o;
}

// transpose-convert: W[k=256][N] f32 -> Wt[N][256] bf16
__global__ void k_wtr(const float* __restrict__ W, u16* __restrict__ Wt, int N){
  int i = blockIdx.x*256 + threadIdx.x;
  if (i >= 256*N) return;
  int k = i / N, n = i % N;
  Wt[(size_t)n*256 + k] = f2b(W[i]);
}

// concat-transpose: [rWo | Wo] -> Wcat_t[320][256] bf16; also init el sentinel row
__global__ void k_catWoT(const float* __restrict__ rWo, const float* __restrict__ Wo, u16* __restrict__ Bct,
                         float* __restrict__ el){
  int i = blockIdx.x*256 + threadIdx.x;
  if (i < 4) el[NN*4 + i] = -1e30f;     // sentinel node for pad edges
  if (i >= 256*320) return;
  int k = i/320, c = i%320;
  float v = (c < 160) ? rWo[k*160 + c] : Wo[k*160 + (c-160)];
  Bct[(size_t)c*256 + k] = f2b(v);
}

// ---------- CSR build (padded: each node segment rounded up to multiple of 8) ----------
__global__ void k_count(const int* __restrict__ dst, int* __restrict__ cnt){
  int i = blockIdx.x*256+threadIdx.x; if (i<EE) atomicAdd(&cnt[dst[i]],1);
}

__global__ void k_scan_blocks(const int* __restrict__ cnt, int* __restrict__ off, int* __restrict__ part, int n){
  __shared__ int ts[256];
  int t = threadIdx.x; int base = blockIdx.x*1024 + t*4;
  int c0 = (base+0<n)?((cnt[base+0]+7)&~7):0;
  int c1 = (base+1<n)?((cnt[base+1]+7)&~7):0;
  int c2 = (base+2<n)?((cnt[base+2]+7)&~7):0;
  int c3 = (base+3<n)?((cnt[base+3]+7)&~7):0;
  int s = c0+c1+c2+c3;
  ts[t]=s; __syncthreads();
  for (int d=1; d<256; d<<=1){ int v=(t>=d)?ts[t-d]:0; __syncthreads(); ts[t]+=v; __syncthreads(); }
  int ex = ts[t]-s;
  if (t==255) part[blockIdx.x]=ts[255];
  if (base+0<n) off[base+0]=ex; ex+=c0;
  if (base+1<n) off[base+1]=ex; ex+=c1;
  if (base+2<n) off[base+2]=ex; ex+=c2;
  if (base+3<n) off[base+3]=ex;
}

__global__ void k_scan_part(int* part, int nb){
  if (threadIdx.x==0 && blockIdx.x==0){ int run=0; for(int i=0;i<nb;++i){ int v=part[i]; part[i]=run; run+=v; } }
}

// addback and also initialize cur = off
__global__ void k_addback(int* off, int* cur, const int* __restrict__ part, int n){
  int base = blockIdx.x*1024 + threadIdx.x*4; int p = part[blockIdx.x];
  #pragma unroll
  for (int j=0;j<4;++j) if (base+j<n){ int v = off[base+j]+p; off[base+j]=v; if (base+j<NN) cur[base+j]=v; }
}

__global__ void k_scatter(const int* __restrict__ src, const int* __restrict__ dst, int* __restrict__ cur,
                          int* __restrict__ srcs){
  int i = blockIdx.x*256+threadIdx.x; if (i>=EE) return;
  int d = dst[i]; int p = atomicAdd(&cur[d],1);
  srcs[p]=src[i];
}

// fill pad slots with sentinel node NN
__global__ void k_padfill(const int* __restrict__ off, const int* __restrict__ cnt, int* __restrict__ srcs){
  int n = blockIdx.x*256+threadIdx.x; if (n>=NN) return;
  int e = off[n]+cnt[n], e1 = off[n+1];
  for (; e<e1; ++e) srcs[e] = NN;
}

// ---------- GEMM2: C[M,:] = A[M,256](bf16) @ Bt[N,256]^T, f32 acc ----------
// BM=128, full-K LDS stage via global_load_lds (pre-swizzled source), 256 thr = 4 waves (2Mx2N)
// MODE 0: f32 out. MODE 1: bf16 out + fused el/er epilogue (64-dim heads). MODE 2: split 160/160 bf16.
template<int BN, int MODE>
__global__ __launch_bounds__(256) void k_gemm2(const u16* __restrict__ A, const u16* __restrict__ Bt,
                                               void* __restrict__ C0, void* __restrict__ C1,
                                               const float* __restrict__ AL, const float* __restrict__ AR,
                                               float* __restrict__ EL, float* __restrict__ ER,
                                               int M, int ldC){
  __shared__ u16 lds[(128+BN)*256];
  u16* As = lds;
  u16* Bs = lds + 128*256;
  const int tid = threadIdx.x;
  const int row0 = blockIdx.x * 128;
  const int n0   = blockIdx.y * BN;
  #pragma unroll
  for (int it=0; it<16; ++it){
    int slot = it*256 + tid;
    int r = slot >> 5, s = slot & 31;
    int gs = s ^ (r & 7);
    const u16* gp = A + (size_t)(row0 + r)*256 + (gs<<3);
    u16* lp = As + (size_t)(it*256 + (tid & ~63))*8;
    __builtin_amdgcn_global_load_lds((const void*)gp, (void*)lp, 16, 0, 0);
  }
  #pragma unroll
  for (int it=0; it<BN/8; ++it){
    int slot = it*256 + tid;
    int r = slot >> 5, s = slot & 31;
    int gs = s ^ (r & 7);
    const u16* gp = Bt + (size_t)(n0 + r)*256 + (gs<<3);
    u16* lp = Bs + (size_t)(it*256 + (tid & ~63))*8;
    __builtin_amdgcn_global_load_lds((const void*)gp, (void*)lp, 16, 0, 0);
  }
  __syncthreads();
  const int wave = tid >> 6, l = tid & 63;
  const int wm = wave >> 1, wn = wave & 1;
  const int lr = l & 15, lq = l >> 4;
  const int NR = BN/32;
  f32x4 acc[4][4];
  #pragma unroll
  for (int mr=0;mr<4;++mr)
    #pragma unroll
    for (int nr=0;nr<NR;++nr) acc[mr][nr]=(f32x4)0.0f;
  #pragma unroll
  for (int kk=0; kk<8; ++kk){
    short8 a[4], b[4];
    #pragma unroll
    for (int mr=0;mr<4;++mr){
      int rloc = wm*64 + mr*16 + lr;
      int byo = rloc*512 + ((kk*64 + lq*16) ^ ((rloc&7)<<4));
      a[mr] = *(const short8*)((const char*)As + byo);
    }
    #pragma unroll
    for (int nr=0;nr<NR;++nr){
      int cloc = wn*(BN/2) + nr*16 + lr;
      int byo = cloc*512 + ((kk*64 + lq*16) ^ ((cloc&7)<<4));
      b[nr] = *(const short8*)((const char*)Bs + byo);
    }
    #pragma unroll
    for (int mr=0;mr<4;++mr)
      #pragma unroll
      for (int nr=0;nr<NR;++nr)
        acc[mr][nr] = __builtin_amdgcn_mfma_f32_16x16x32_bf16(a[mr], b[nr], acc[mr][nr], 0, 0, 0);
  }
  #pragma unroll
  for (int mr=0;mr<4;++mr)
    #pragma unroll
    for (int nr=0;nr<NR;++nr)
      #pragma unroll
      for (int q=0;q<4;++q){
        int r = row0 + wm*64 + mr*16 + lq*4 + q;
        if (r < M){
          int c = n0 + wn*(BN/2) + nr*16 + lr;
          float v = acc[mr][nr][q];
          if constexpr (MODE == 0)      ((float*)C0)[(size_t)r*ldC + c] = v;
          else if constexpr (MODE == 1) ((u16*)C0)[(size_t)r*ldC + c] = f2b(v);
          else {
            if (c < 160)      ((u16*)C0)[(size_t)r*160 + c]       = f2b(v);
            else if (c < 320) ((u16*)C1)[(size_t)r*160 + (c-160)] = f2b(v);
          }
        }
      }
  if constexpr (MODE == 1){
    // fused el/er: this wave's 64-col span is exactly one 64-dim head
    const int head = (n0 + wn*64) >> 6;
    float alc[4], arc[4];
    #pragma unroll
    for (int nr=0;nr<4;++nr){
      int c = n0 + wn*64 + nr*16 + lr;
      alc[nr] = AL[c]; arc[nr] = AR[c];
    }
    #pragma unroll
    for (int mr=0;mr<4;++mr)
      #pragma unroll
      for (int q=0;q<4;++q){
        float suml = acc[mr][0][q]*alc[0] + acc[mr][1][q]*alc[1] + acc[mr][2][q]*alc[2] + acc[mr][3][q]*alc[3];
        float sumr = acc[mr][0][q]*arc[0] + acc[mr][1][q]*arc[1] + acc[mr][2][q]*arc[2] + acc[mr][3][q]*arc[3];
        #pragma unroll
        for (int msk=1; msk<16; msk<<=1){ suml += __shfl_xor(suml,msk,64); sumr += __shfl_xor(sumr,msk,64); }
        int r = row0 + wm*64 + mr*16 + lq*4 + q;
        if (lr == 0 && r < M){ EL[r*4+head] = suml; ER[r*4+head] = sumr; }
      }
  }
}

// ---------- generic el/er (output layer: Dh=40, HD=160) ----------
__global__ void k_eler(const u16* __restrict__ feat, const float* __restrict__ al, const float* __restrict__ ar,
                       float* __restrict__ el, float* __restrict__ er, int Dh, int HD){
  int t = blockIdx.x*256 + threadIdx.x;
  int n = t >> 6; int l = t & 63;
  if (n >= NN) return;
  int h = l >> 4, s = l & 15;
  const u16* fr = feat + (size_t)n*HD + h*Dh;
  const float* alh = al + h*Dh; const float* arh = ar + h*Dh;
  float accl = 0.f, accr = 0.f;
  for (int d = s; d < Dh; d += 16){ float f = b2f(fr[d]); accl += f*alh[d]; accr += f*arh[d]; }
  #pragma unroll
  for (int m = 8; m >= 1; m >>= 1){ accl += __shfl_xor(accl, m, 64); accr += __shfl_xor(accr, m, 64); }
  if (s == 0){ el[n*4+h] = accl; er[n*4+h] = accr; }
}

// ---------- phase A: per-node sum of p (no stores); rc in registers ----------
__device__ __forceinline__ float4 rc_prefix(const float* __restrict__ el, float4 e4,
    const int* __restrict__ srcs, int o0, int o1p, int l){
  float4 s; s.x=s.y=s.z=s.w=0.f;
  for (int e = o0 + l; e < o1p; e += 64){
    float4 a = ((const float4*)el)[srcs[e]];   // pad -> sentinel row, exp -> 0
    s.x += pexp(a.x+e4.x);
    s.y += pexp(a.y+e4.y);
    s.z += pexp(a.z+e4.z);
    s.w += pexp(a.w+e4.w);
  }
  #pragma unroll
  for (int msk=1; msk<64; msk<<=1){
    s.x+=__shfl_xor(s.x,msk,64); s.y+=__shfl_xor(s.y,msk,64);
    s.z+=__shfl_xor(s.z,msk,64); s.w+=__shfl_xor(s.w,msk,64);
  }
  float4 rc;
  rc.x = s.x>0.f ? 1.f/s.x : 0.f;
  rc.y = s.y>0.f ? 1.f/s.y : 0.f;
  rc.z = s.z>0.f ? 1.f/s.z : 0.f;
  rc.w = s.w>0.f ? 1.f/s.w : 0.f;
  return rc;
}

// ---------- D=64 aggregation, fully fused softmax (recompute-p); wave/node, half-wave pairs ----------
template<bool RES>
__global__ __launch_bounds__(256) void k_agg64(const u16* __restrict__ feat,
    const float* __restrict__ el, const float* __restrict__ er,
    const int* __restrict__ off, const int* __restrict__ srcs,
    const u16* __restrict__ resid, float* __restrict__ outf, u16* __restrict__ outb){
  const int l = threadIdx.x & 63, w = threadIdx.x >> 6;
  const int n = blockIdx.x*4 + w;
  const int o0 = off[n], o1p = off[n+1];
  float4 e4 = ((const float4*)er)[n];
  float4 rc4 = rc_prefix(el, e4, srcs, o0, o1p, l);
  const int lh = l & 31;
  const int half = l >> 5;
  const int h = lh >> 3;
  const float rch = ((const float*)&rc4)[h];
  const float erh = ((const float*)&e4)[h];
  float a0=0.f,a1=0.f,a2=0.f,a3=0.f,a4=0.f,a5=0.f,a6=0.f,a7=0.f;
  for (int i = o0; i < o1p; i += 8){
    #pragma unroll
    for (int u=0; u<4; ++u){
      int e = i + u*2 + half;
      int sv = srcs[e];
      float p = pexp(el[sv*4 + h] + erh);
      short8 f = *(const short8*)(feat + (size_t)sv*256 + lh*8);
      a0 += p*b2f((u16)f[0]); a1 += p*b2f((u16)f[1]);
      a2 += p*b2f((u16)f[2]); a3 += p*b2f((u16)f[3]);
      a4 += p*b2f((u16)f[4]); a5 += p*b2f((u16)f[5]);
      a6 += p*b2f((u16)f[6]); a7 += p*b2f((u16)f[7]);
    }
  }
  a0 += __shfl_xor(a0,32,64); a1 += __shfl_xor(a1,32,64);
  a2 += __shfl_xor(a2,32,64); a3 += __shfl_xor(a3,32,64);
  a4 += __shfl_xor(a4,32,64); a5 += __shfl_xor(a5,32,64);
  a6 += __shfl_xor(a6,32,64); a7 += __shfl_xor(a7,32,64);
  if (half == 0){
    float v[8] = {a0*rch,a1*rch,a2*rch,a3*rch,a4*rch,a5*rch,a6*rch,a7*rch};
    if (RES){
      short8 r8 = *(const short8*)(resid + (size_t)n*256 + lh*8);
      #pragma unroll
      for (int j=0;j<8;++j) v[j] += b2f((u16)r8[j]);
    }
    #pragma unroll
    for (int j=0;j<8;++j) v[j] = v[j] > 0.f ? v[j] : expm1f(v[j]);
    if (outf){
      float4 q0; q0.x=v[0]; q0.y=v[1]; q0.z=v[2]; q0.w=v[3];
      float4 q1; q1.x=v[4]; q1.y=v[5]; q1.z=v[6]; q1.w=v[7];
      *(float4*)(outf + (size_t)n*256 + lh*8)     = q0;
      *(float4*)(outf + (size_t)n*256 + lh*8 + 4) = q1;
    }
    short8 ob;
    #pragma unroll
    for (int j=0;j<8;++j) ob[j] = (short)f2b(v[j]);
    *(short8*)(outb + (size_t)n*256 + lh*8) = ob;
  }
}

// ---------- output-layer aggregation, fused softmax (recompute-p): 8-edge groups, ushort8 loads ----------
__global__ __launch_bounds__(256) void k_agg_out(const u16* __restrict__ feat,
    const float* __restrict__ el, const float* __restrict__ er,
    const int* __restrict__ off, const int* __restrict__ srcs,
    const u16* __restrict__ reso, float* __restrict__ logits){
  __shared__ float red[4][8][20][8];
  __shared__ float fin[4][160];
  const int l = threadIdx.x & 63, w = threadIdx.x >> 6;
  const int n = blockIdx.x*4 + w;
  const int o0 = off[n], o1p = off[n+1];
  float4 e4 = ((const float4*)er)[n];
  float4 rc4 = rc_prefix(el, e4, srcs, o0, o1p, l);
  const int s0 = l/20,        q0 = l%20;
  const int s1 = (64+l)/20,   q1 = (64+l)%20;
  const int s2 = (128+l)/20,  q2 = (128+l)%20;   // active l<32
  const int h0 = q0/5, h1 = q1/5, h2 = q2/5;
  const float er0 = ((const float*)&e4)[h0], er1 = ((const float*)&e4)[h1], er2 = ((const float*)&e4)[h2];
  float acc0[8], acc1[8], acc2[8];
  #pragma unroll
  for (int j=0;j<8;++j){ acc0[j]=0.f; acc1[j]=0.f; acc2[j]=0.f; }
  for (int i0 = o0; i0 < o1p; i0 += 8){
    {
      int e = i0 + s0; int sv = srcs[e]; float p = pexp(el[sv*4+h0] + er0);
      short8 f = *(const short8*)(feat + (size_t)sv*160 + q0*8);
      #pragma unroll
      for (int j=0;j<8;++j) acc0[j] += p*b2f((u16)f[j]);
    }
    {
      int e = i0 + s1; int sv = srcs[e]; float p = pexp(el[sv*4+h1] + er1);
      short8 f = *(const short8*)(feat + (size_t)sv*160 + q1*8);
      #pragma unroll
      for (int j=0;j<8;++j) acc1[j] += p*b2f((u16)f[j]);
    }
    if (l < 32){
      int e = i0 + s2; int sv = srcs[e]; float p = pexp(el[sv*4+h2] + er2);
      short8 f = *(const short8*)(feat + (size_t)sv*160 + q2*8);
      #pragma unroll
      for (int j=0;j<8;++j) acc2[j] += p*b2f((u16)f[j]);
    }
  }
  #pragma unroll
  for (int j=0;j<8;++j) red[w][s0][q0][j] = acc0[j];
  #pragma unroll
  for (int j=0;j<8;++j) red[w][s1][q1][j] = acc1[j];
  if (l < 32){
    #pragma unroll
    for (int j=0;j<8;++j) red[w][s2][q2][j] = acc2[j];
  }
  __syncthreads();
  if (l < 20){
    const int q = l;
    float rc = ((const float*)&rc4)[q/5];
    short8 rr = *(const short8*)(reso + (size_t)n*160 + q*8);
    #pragma unroll
    for (int j=0;j<8;++j){
      float v = red[w][0][q][j];
      #pragma unroll
      for (int s=1;s<8;++s) v += red[w][s][q][j];
      fin[w][q*8+j] = v*rc + b2f((u16)rr[j]);
    }
  }
  __syncthreads();
  if (l < 40) logits[(size_t)n*40 + l] = 0.25f*(fin[w][l]+fin[w][l+40]+fin[w][l+80]+fin[w][l+120]);
}

extern "C" void kernel_launch(void* const* d_in, const int* in_sizes, int n_in,
                              void* d_out, int out_size, void* d_ws, size_t ws_size,
                              hipStream_t stream){
  const float* inputs = (const float*)d_in[0];
  const int*   src    = (const int*)d_in[1];
  const int*   dst    = (const int*)d_in[2];
  const float* W0  = (const float*)d_in[3];
  const float* al0 = (const float*)d_in[4];
  const float* ar0 = (const float*)d_in[5];
  const float* W1  = (const float*)d_in[6];
  const float* al1 = (const float*)d_in[7];
  const float* ar1 = (const float*)d_in[8];
  const float* Wo  = (const float*)d_in[9];
  const float* alo = (const float*)d_in[10];
  const float* aro = (const float*)d_in[11];
  const float* rWo = (const float*)d_in[12];
  const float* fcW = (const float*)d_in[13];

  float* out = (float*)d_out;
  float* out_logits = out;                 // [50000,40]
  float* out_h      = out + 2000000;       // [50000,256]
  float* out_seq    = out + 14800000;      // [50000,64]

  char* ws = (char*)d_ws;
  size_t o = 0;
  auto alc = [&](size_t bytes){ size_t r = o; o += (bytes + 255) & ~(size_t)255; return r; };
  size_t oXb   = alc((size_t)NN*256*2);
  size_t oFA   = alc((size_t)NN*256*2);
  size_t oFB   = alc((size_t)NN*256*2);
  size_t oSrcs = alc((size_t)EPAD*4);
  size_t oOff  = alc((size_t)(NN+1)*4);
  size_t oCnt  = alc((size_t)(NN+1)*4);
  size_t oCur  = alc((size_t)NN*4);
  size_t oPart = alc(64*4);
  size_t oEl   = alc((size_t)(NN+1)*4*4);   // +1 sentinel row
  size_t oEr   = alc((size_t)NN*4*4);
  size_t oReso = alc((size_t)NN*160*2);
  size_t oW0t  = alc(256*256*2);
  size_t oW1t  = alc(256*256*2);
  size_t oWct  = alc((size_t)384*256*2);
  size_t oFct  = alc((size_t)128*256*2);
  if (ws_size < o) return;

  u16* Xb   = (u16*)(ws + oXb);
  u16* fA   = (u16*)(ws + oFA);
  u16* fB   = (u16*)(ws + oFB);
  int* srcs = (int*)(ws + oSrcs);
  int* off  = (int*)(ws + oOff);
  int* cnt  = (int*)(ws + oCnt);
  int* cur  = (int*)(ws + oCur);
  int* part = (int*)(ws + oPart);
  float* el = (float*)(ws + oEl);
  float* er = (float*)(ws + oEr);
  u16* reso = (u16*)(ws + oReso);
  u16* W0t  = (u16*)(ws + oW0t);
  u16* W1t  = (u16*)(ws + oW1t);
  u16* Wct  = (u16*)(ws + oWct);
  u16* fct  = (u16*)(ws + oFct);

  // ---- converts (weights transposed for GEMM2 B-staging) + el sentinel ----
  k_f2b4<<<(NN*256/4 + 255)/256, 256, 0, stream>>>(inputs, Xb, NN*256/4);
  k_wtr<<<(256*256 + 255)/256, 256, 0, stream>>>(W0, W0t, 256);
  k_wtr<<<(256*256 + 255)/256, 256, 0, stream>>>(W1, W1t, 256);
  k_wtr<<<(256*64 + 255)/256, 256, 0, stream>>>(fcW, fct, 64);
  k_catWoT<<<(256*320 + 255)/256, 256, 0, stream>>>(rWo, Wo, Wct, el);

  // ---- CSR (padded, pad slots -> sentinel node NN) ----
  hipMemsetAsync(cnt, 0, (size_t)(NN+1)*4, stream);
  k_count<<<(EE+255)/256, 256, 0, stream>>>(dst, cnt);
  const int NP1 = NN+1, NB = (NP1 + 1023)/1024;
  k_scan_blocks<<<NB, 256, 0, stream>>>(cnt, off, part, NP1);
  k_scan_part<<<1, 64, 0, stream>>>(part, NB);
  k_addback<<<NB, 256, 0, stream>>>(off, cur, part, NP1);
  k_scatter<<<(EE+255)/256, 256, 0, stream>>>(src, dst, cur, srcs);
  k_padfill<<<(NN+255)/256, 256, 0, stream>>>(off, cnt, srcs);

  const int GX = (NN + 127)/128;   // 391
  dim3 g256(GX, 2), g320(GX, 3), g64(GX, 1);

  // ---- seq_fts = X @ fc_W (f32 out) ----
  k_gemm2<64,0><<<g64, 256, 0, stream>>>(Xb, fct, out_seq, nullptr, nullptr, nullptr, nullptr, nullptr, NN, 64);

  // ---- layer 0: GEMM(+el/er) -> agg(+fused softmax) ----
  k_gemm2<128,1><<<g256, 256, 0, stream>>>(Xb, W0t, fA, nullptr, al0, ar0, el, er, NN, 256);
  k_agg64<false><<<NN/4, 256, 0, stream>>>(fA, el, er, off, srcs, nullptr, nullptr, fB);

  // ---- layer 1 ----
  k_gemm2<128,1><<<g256, 256, 0, stream>>>(fB, W1t, fA, nullptr, al1, ar1, el, er, NN, 256);
  k_agg64<true><<<NN/4, 256, 0, stream>>>(fA, el, er, off, srcs, fB, out_h, fB);

  // ---- output layer: fused [reso | Wo] GEMM -> eler -> agg(+fused softmax) ----
  k_gemm2<128,2><<<g320, 256, 0, stream>>>(fB, Wct, reso, fA, nullptr, nullptr, nullptr, nullptr, NN, 320);
  k_eler<<<(NN*64 + 255)/256, 256, 0, stream>>>(fA, alo, aro, el, er, 40, 160);
  k_agg_out<<<NN/4, 256, 0, stream>>>(fA, el, er, off, srcs, reso, out_logits);
}

// Round 8
// 492.400 us; speedup vs baseline: 1.0822x; 1.0822x over previous
//
#include <hip/hip_runtime.h>

typedef unsigned short u16;
typedef unsigned int u32;
typedef __attribute__((ext_vector_type(8))) short short8;
typedef __attribute__((ext_vector_type(4))) float f32x4;

#define NN 50000
#define EE 800000
#define EPAD (EE + 8*NN)   // max padded edges = 1,200,000

__device__ __forceinline__ float b2f(u16 u){ union{float f;u32 i;}x; x.i=((u32)u)<<16; return x.f; }
__device__ __forceinline__ u16 f2b(float f){ union{float f;u32 i;}x; x.f=f; u32 i=x.i; return (u16)((i + 0x7fffu + ((i>>16)&1u))>>16); }

// ---------- converts ----------
__global__ void k_f2b4(const float* __restrict__ x, u16* __restrict__ y, int n4){
  int i = blockIdx.x*256 + threadIdx.x;
  if (i >= n4) return;
  float4 v = ((const float4*)x)[i];
  ushort4 o; o.x=f2b(v.x); o.y=f2b(v.y); o.z=f2b(v.z); o.w=f2b(v.w);
  ((ushort4*)y)[i]=o;
}

// transpose-convert: W[k=256][N] f32 -> Wt[N][256] bf16
__global__ void k_wtr(const float* __restrict__ W, u16* __restrict__ Wt, int N){
  int i = blockIdx.x*256 + threadIdx.x;
  if (i >= 256*N) return;
  int k = i / N, n = i % N;
  Wt[(size_t)n*256 + k] = f2b(W[i]);
}

// concat-transpose: [rWo | Wo] (each [256][160]) -> Wcat_t[320][256] bf16
__global__ void k_catWoT(const float* __restrict__ rWo, const float* __restrict__ Wo, u16* __restrict__ Bct){
  int i = blockIdx.x*256 + threadIdx.x;
  if (i >= 256*320) return;
  int k = i/320, c = i%320;
  float v = (c < 160) ? rWo[k*160 + c] : Wo[k*160 + (c-160)];
  Bct[(size_t)c*256 + k] = f2b(v);
}

// ---------- CSR build (padded: each node segment rounded up to multiple of 8) ----------
__global__ void k_count(const int* __restrict__ dst, int* __restrict__ cnt){
  int i = blockIdx.x*256+threadIdx.x; if (i<EE) atomicAdd(&cnt[dst[i]],1);
}

__global__ void k_scan_blocks(const int* __restrict__ cnt, int* __restrict__ off, int* __restrict__ part, int n){
  __shared__ int ts[256];
  int t = threadIdx.x; int base = blockIdx.x*1024 + t*4;
  int c0 = (base+0<n)?((cnt[base+0]+7)&~7):0;
  int c1 = (base+1<n)?((cnt[base+1]+7)&~7):0;
  int c2 = (base+2<n)?((cnt[base+2]+7)&~7):0;
  int c3 = (base+3<n)?((cnt[base+3]+7)&~7):0;
  int s = c0+c1+c2+c3;
  ts[t]=s; __syncthreads();
  for (int d=1; d<256; d<<=1){ int v=(t>=d)?ts[t-d]:0; __syncthreads(); ts[t]+=v; __syncthreads(); }
  int ex = ts[t]-s;
  if (t==255) part[blockIdx.x]=ts[255];
  if (base+0<n) off[base+0]=ex; ex+=c0;
  if (base+1<n) off[base+1]=ex; ex+=c1;
  if (base+2<n) off[base+2]=ex; ex+=c2;
  if (base+3<n) off[base+3]=ex;
}

__global__ void k_scan_part(int* part, int nb){
  if (threadIdx.x==0 && blockIdx.x==0){ int run=0; for(int i=0;i<nb;++i){ int v=part[i]; part[i]=run; run+=v; } }
}

// addback and also initialize cur = off
__global__ void k_addback(int* off, int* cur, const int* __restrict__ part, int n){
  int base = blockIdx.x*1024 + threadIdx.x*4; int p = part[blockIdx.x];
  #pragma unroll
  for (int j=0;j<4;++j) if (base+j<n){ int v = off[base+j]+p; off[base+j]=v; if (base+j<NN) cur[base+j]=v; }
}

__global__ void k_scatter(const int* __restrict__ src, const int* __restrict__ dst, int* __restrict__ cur,
                          int* __restrict__ srcs){
  int i = blockIdx.x*256+threadIdx.x; if (i>=EE) return;
  int d = dst[i]; int p = atomicAdd(&cur[d],1);
  srcs[p]=src[i];
}

// fill pad slots with node 0 (es for pads is zeroed by k_soft, so contribution is 0)
__global__ void k_padfill(const int* __restrict__ off, const int* __restrict__ cnt, int* __restrict__ srcs){
  int n = blockIdx.x*256+threadIdx.x; if (n>=NN) return;
  int e = off[n]+cnt[n], e1 = off[n+1];
  for (; e<e1; ++e) srcs[e] = 0;
}

// ---------- GEMM2: C[M,:] = A[M,256](bf16) @ Bt[N,256]^T, f32 acc ----------
// BM=128, full-K LDS stage via global_load_lds (pre-swizzled source), 256 thr = 4 waves (2Mx2N)
// MODE 0: f32 out. MODE 1: bf16 out + fused el/er epilogue (64-dim heads). MODE 2: split 160/160 bf16.
template<int BN, int MODE>
__global__ __launch_bounds__(256) void k_gemm2(const u16* __restrict__ A, const u16* __restrict__ Bt,
                                               void* __restrict__ C0, void* __restrict__ C1,
                                               const float* __restrict__ AL, const float* __restrict__ AR,
                                               float* __restrict__ EL, float* __restrict__ ER,
                                               int M, int ldC){
  __shared__ u16 lds[(128+BN)*256];
  u16* As = lds;
  u16* Bs = lds + 128*256;
  const int tid = threadIdx.x;
  const int row0 = blockIdx.x * 128;
  const int n0   = blockIdx.y * BN;
  #pragma unroll
  for (int it=0; it<16; ++it){
    int slot = it*256 + tid;
    int r = slot >> 5, s = slot & 31;
    int gs = s ^ (r & 7);
    const u16* gp = A + (size_t)(row0 + r)*256 + (gs<<3);
    u16* lp = As + (size_t)(it*256 + (tid & ~63))*8;
    __builtin_amdgcn_global_load_lds((const void*)gp, (void*)lp, 16, 0, 0);
  }
  #pragma unroll
  for (int it=0; it<BN/8; ++it){
    int slot = it*256 + tid;
    int r = slot >> 5, s = slot & 31;
    int gs = s ^ (r & 7);
    const u16* gp = Bt + (size_t)(n0 + r)*256 + (gs<<3);
    u16* lp = Bs + (size_t)(it*256 + (tid & ~63))*8;
    __builtin_amdgcn_global_load_lds((const void*)gp, (void*)lp, 16, 0, 0);
  }
  __syncthreads();
  const int wave = tid >> 6, l = tid & 63;
  const int wm = wave >> 1, wn = wave & 1;
  const int lr = l & 15, lq = l >> 4;
  const int NR = BN/32;
  f32x4 acc[4][4];
  #pragma unroll
  for (int mr=0;mr<4;++mr)
    #pragma unroll
    for (int nr=0;nr<NR;++nr) acc[mr][nr]=(f32x4)0.0f;
  #pragma unroll
  for (int kk=0; kk<8; ++kk){
    short8 a[4], b[4];
    #pragma unroll
    for (int mr=0;mr<4;++mr){
      int rloc = wm*64 + mr*16 + lr;
      int byo = rloc*512 + ((kk*64 + lq*16) ^ ((rloc&7)<<4));
      a[mr] = *(const short8*)((const char*)As + byo);
    }
    #pragma unroll
    for (int nr=0;nr<NR;++nr){
      int cloc = wn*(BN/2) + nr*16 + lr;
      int byo = cloc*512 + ((kk*64 + lq*16) ^ ((cloc&7)<<4));
      b[nr] = *(const short8*)((const char*)Bs + byo);
    }
    #pragma unroll
    for (int mr=0;mr<4;++mr)
      #pragma unroll
      for (int nr=0;nr<NR;++nr)
        acc[mr][nr] = __builtin_amdgcn_mfma_f32_16x16x32_bf16(a[mr], b[nr], acc[mr][nr], 0, 0, 0);
  }
  #pragma unroll
  for (int mr=0;mr<4;++mr)
    #pragma unroll
    for (int nr=0;nr<NR;++nr)
      #pragma unroll
      for (int q=0;q<4;++q){
        int r = row0 + wm*64 + mr*16 + lq*4 + q;
        if (r < M){
          int c = n0 + wn*(BN/2) + nr*16 + lr;
          float v = acc[mr][nr][q];
          if constexpr (MODE == 0)      ((float*)C0)[(size_t)r*ldC + c] = v;
          else if constexpr (MODE == 1) ((u16*)C0)[(size_t)r*ldC + c] = f2b(v);
          else {
            if (c < 160)      ((u16*)C0)[(size_t)r*160 + c]       = f2b(v);
            else if (c < 320) ((u16*)C1)[(size_t)r*160 + (c-160)] = f2b(v);
          }
        }
      }
  if constexpr (MODE == 1){
    // fused el/er: this wave's 64-col span is exactly one 64-dim head
    const int head = (n0 + wn*64) >> 6;
    float alc[4], arc[4];
    #pragma unroll
    for (int nr=0;nr<4;++nr){
      int c = n0 + wn*64 + nr*16 + lr;
      alc[nr] = AL[c]; arc[nr] = AR[c];
    }
    #pragma unroll
    for (int mr=0;mr<4;++mr)
      #pragma unroll
      for (int q=0;q<4;++q){
        float suml = acc[mr][0][q]*alc[0] + acc[mr][1][q]*alc[1] + acc[mr][2][q]*alc[2] + acc[mr][3][q]*alc[3];
        float sumr = acc[mr][0][q]*arc[0] + acc[mr][1][q]*arc[1] + acc[mr][2][q]*arc[2] + acc[mr][3][q]*arc[3];
        #pragma unroll
        for (int msk=1; msk<16; msk<<=1){ suml += __shfl_xor(suml,msk,64); sumr += __shfl_xor(sumr,msk,64); }
        int r = row0 + wm*64 + mr*16 + lq*4 + q;
        if (lr == 0 && r < M){ EL[r*4+head] = suml; ER[r*4+head] = sumr; }
      }
  }
}

// ---------- generic el/er (output layer: Dh=40, HD=160) ----------
__global__ void k_eler(const u16* __restrict__ feat, const float* __restrict__ al, const float* __restrict__ ar,
                       float* __restrict__ el, float* __restrict__ er, int Dh, int HD){
  int t = blockIdx.x*256 + threadIdx.x;
  int n = t >> 6; int l = t & 63;
  if (n >= NN) return;
  int h = l >> 4, s = l & 15;
  const u16* fr = feat + (size_t)n*HD + h*Dh;
  const float* alh = al + h*Dh; const float* arh = ar + h*Dh;
  float accl = 0.f, accr = 0.f;
  for (int d = s; d < Dh; d += 16){ float f = b2f(fr[d]); accl += f*alh[d]; accr += f*arh[d]; }
  #pragma unroll
  for (int m = 8; m >= 1; m >>= 1){ accl += __shfl_xor(accl, m, 64); accr += __shfl_xor(accr, m, 64); }
  if (s == 0){ el[n*4+h] = accl; er[n*4+h] = accr; }
}

// ---------- edge-parallel softmax: 16 lanes per node (R4-proven) ----------
__global__ void k_soft(const float* __restrict__ el, const float* __restrict__ er,
                       const int* __restrict__ srcs, const int* __restrict__ off, const int* __restrict__ cnt,
                       float* __restrict__ es, float* __restrict__ recs){
  int t = blockIdx.x*256 + threadIdx.x;
  int n = t >> 4; if (n >= NN) return;
  int g = t & 15;
  int o0 = off[n], o1p = off[n+1];
  int deg = cnt[n];
  int oend = o0 + deg;
  float4 e4 = ((const float4*)er)[n];
  float4 m; m.x=m.y=m.z=m.w=-1e30f;
  for (int c = o0 + g; c < oend; c += 16){
    float4 a = ((const float4*)el)[srcs[c]];
    float4 v;
    v.x=a.x+e4.x; v.x = v.x>=0.f?v.x:0.2f*v.x;
    v.y=a.y+e4.y; v.y = v.y>=0.f?v.y:0.2f*v.y;
    v.z=a.z+e4.z; v.z = v.z>=0.f?v.z:0.2f*v.z;
    v.w=a.w+e4.w; v.w = v.w>=0.f?v.w:0.2f*v.w;
    ((float4*)es)[c]=v;
    m.x=fmaxf(m.x,v.x); m.y=fmaxf(m.y,v.y); m.z=fmaxf(m.z,v.z); m.w=fmaxf(m.w,v.w);
  }
  { int cp = oend + g; if (cp < o1p){ float4 z; z.x=z.y=z.z=z.w=0.f; ((float4*)es)[cp]=z; } }
  #pragma unroll
  for (int msk = 8; msk >= 1; msk >>= 1){
    m.x=fmaxf(m.x,__shfl_xor(m.x,msk,64)); m.y=fmaxf(m.y,__shfl_xor(m.y,msk,64));
    m.z=fmaxf(m.z,__shfl_xor(m.z,msk,64)); m.w=fmaxf(m.w,__shfl_xor(m.w,msk,64));
  }
  float4 s; s.x=s.y=s.z=s.w=0.f;
  for (int c = o0 + g; c < oend; c += 16){
    float4 v = ((const float4*)es)[c];
    v.x=__expf(v.x-m.x); v.y=__expf(v.y-m.y); v.z=__expf(v.z-m.z); v.w=__expf(v.w-m.w);
    ((float4*)es)[c]=v; s.x+=v.x; s.y+=v.y; s.z+=v.z; s.w+=v.w;
  }
  #pragma unroll
  for (int msk = 8; msk >= 1; msk >>= 1){
    s.x+=__shfl_xor(s.x,msk,64); s.y+=__shfl_xor(s.y,msk,64);
    s.z+=__shfl_xor(s.z,msk,64); s.w+=__shfl_xor(s.w,msk,64);
  }
  if (g == 0){
    float4 r;
    r.x = s.x>0.f ? 1.f/s.x : 0.f;
    r.y = s.y>0.f ? 1.f/s.y : 0.f;
    r.z = s.z>0.f ? 1.f/s.z : 0.f;
    r.w = s.w>0.f ? 1.f/s.w : 0.f;
    ((float4*)recs)[n] = r;
  }
}

// ---------- D=64 aggregation (R4-proven): wave per node, half-wave pairs, 8-edge unroll ----------
template<bool RES>
__global__ __launch_bounds__(256) void k_agg64(const u16* __restrict__ feat, const float* __restrict__ es,
    const float* __restrict__ recs, const int* __restrict__ off, const int* __restrict__ srcs,
    const u16* __restrict__ resid, float* __restrict__ outf, u16* __restrict__ outb){
  const int l = threadIdx.x & 63, w = threadIdx.x >> 6;
  const int n = blockIdx.x*4 + w;
  const int o0 = off[n], o1p = off[n+1];
  const int lh = l & 31;
  const int half = l >> 5;
  const int h = lh >> 3;
  float a0=0.f,a1=0.f,a2=0.f,a3=0.f,a4=0.f,a5=0.f,a6=0.f,a7=0.f;
  for (int i = o0; i < o1p; i += 8){
    #pragma unroll
    for (int u=0; u<4; ++u){
      int e = i + u*2 + half;
      int sv = srcs[e];
      float al = es[(size_t)e*4 + h];
      short8 f = *(const short8*)(feat + (size_t)sv*256 + lh*8);
      a0 += al*b2f((u16)f[0]); a1 += al*b2f((u16)f[1]);
      a2 += al*b2f((u16)f[2]); a3 += al*b2f((u16)f[3]);
      a4 += al*b2f((u16)f[4]); a5 += al*b2f((u16)f[5]);
      a6 += al*b2f((u16)f[6]); a7 += al*b2f((u16)f[7]);
    }
  }
  a0 += __shfl_xor(a0,32,64); a1 += __shfl_xor(a1,32,64);
  a2 += __shfl_xor(a2,32,64); a3 += __shfl_xor(a3,32,64);
  a4 += __shfl_xor(a4,32,64); a5 += __shfl_xor(a5,32,64);
  a6 += __shfl_xor(a6,32,64); a7 += __shfl_xor(a7,32,64);
  if (half == 0){
    float rc = recs[n*4+h];
    float v[8] = {a0*rc,a1*rc,a2*rc,a3*rc,a4*rc,a5*rc,a6*rc,a7*rc};
    if (RES){
      short8 r8 = *(const short8*)(resid + (size_t)n*256 + lh*8);
      #pragma unroll
      for (int j=0;j<8;++j) v[j] += b2f((u16)r8[j]);
    }
    #pragma unroll
    for (int j=0;j<8;++j) v[j] = v[j] > 0.f ? v[j] : expm1f(v[j]);
    if (outf){
      float4 q0; q0.x=v[0]; q0.y=v[1]; q0.z=v[2]; q0.w=v[3];
      float4 q1; q1.x=v[4]; q1.y=v[5]; q1.z=v[6]; q1.w=v[7];
      *(float4*)(outf + (size_t)n*256 + lh*8)     = q0;
      *(float4*)(outf + (size_t)n*256 + lh*8 + 4) = q1;
    }
    short8 ob;
    #pragma unroll
    for (int j=0;j<8;++j) ob[j] = (short)f2b(v[j]);
    *(short8*)(outb + (size_t)n*256 + lh*8) = ob;
  }
}

// ---------- output-layer aggregation: 8-edge groups, ushort8 loads, bank-conflict-free red ----------
__global__ __launch_bounds__(256) void k_agg_out(const u16* __restrict__ feat, const float* __restrict__ es,
    const float* __restrict__ recs, const int* __restrict__ off, const int* __restrict__ srcs,
    const u16* __restrict__ reso, float* __restrict__ logits){
  __shared__ float red[4][8][20][9];   // [..][9]: 9 coprime 32 -> conflict-free stores
  __shared__ float fin[4][160];
  const int l = threadIdx.x & 63, w = threadIdx.x >> 6;
  const int n = blockIdx.x*4 + w;
  const int o0 = off[n], o1p = off[n+1];
  const int s0 = l/20,        q0 = l%20;
  const int s1 = (64+l)/20,   q1 = (64+l)%20;
  const int s2 = (128+l)/20,  q2 = (128+l)%20;   // active l<32
  const int h0 = q0/5, h1 = q1/5, h2 = q2/5;
  float acc0[8], acc1[8], acc2[8];
  #pragma unroll
  for (int j=0;j<8;++j){ acc0[j]=0.f; acc1[j]=0.f; acc2[j]=0.f; }
  for (int i0 = o0; i0 < o1p; i0 += 8){
    {
      int e = i0 + s0; int sv = srcs[e]; float al = es[(size_t)e*4 + h0];
      short8 f = *(const short8*)(feat + (size_t)sv*160 + q0*8);
      #pragma unroll
      for (int j=0;j<8;++j) acc0[j] += al*b2f((u16)f[j]);
    }
    {
      int e = i0 + s1; int sv = srcs[e]; float al = es[(size_t)e*4 + h1];
      short8 f = *(const short8*)(feat + (size_t)sv*160 + q1*8);
      #pragma unroll
      for (int j=0;j<8;++j) acc1[j] += al*b2f((u16)f[j]);
    }
    if (l < 32){
      int e = i0 + s2; int sv = srcs[e]; float al = es[(size_t)e*4 + h2];
      short8 f = *(const short8*)(feat + (size_t)sv*160 + q2*8);
      #pragma unroll
      for (int j=0;j<8;++j) acc2[j] += al*b2f((u16)f[j]);
    }
  }
  #pragma unroll
  for (int j=0;j<8;++j) red[w][s0][q0][j] = acc0[j];
  #pragma unroll
  for (int j=0;j<8;++j) red[w][s1][q1][j] = acc1[j];
  if (l < 32){
    #pragma unroll
    for (int j=0;j<8;++j) red[w][s2][q2][j] = acc2[j];
  }
  __syncthreads();
  if (l < 20){
    const int q = l;
    float rc = recs[n*4 + q/5];
    short8 rr = *(const short8*)(reso + (size_t)n*160 + q*8);
    #pragma unroll
    for (int j=0;j<8;++j){
      float v = red[w][0][q][j];
      #pragma unroll
      for (int s=1;s<8;++s) v += red[w][s][q][j];
      fin[w][q*8+j] = v*rc + b2f((u16)rr[j]);
    }
  }
  __syncthreads();
  if (l < 40) logits[(size_t)n*40 + l] = 0.25f*(fin[w][l]+fin[w][l+40]+fin[w][l+80]+fin[w][l+120]);
}

extern "C" void kernel_launch(void* const* d_in, const int* in_sizes, int n_in,
                              void* d_out, int out_size, void* d_ws, size_t ws_size,
                              hipStream_t stream){
  const float* inputs = (const float*)d_in[0];
  const int*   src    = (const int*)d_in[1];
  const int*   dst    = (const int*)d_in[2];
  const float* W0  = (const float*)d_in[3];
  const float* al0 = (const float*)d_in[4];
  const float* ar0 = (const float*)d_in[5];
  const float* W1  = (const float*)d_in[6];
  const float* al1 = (const float*)d_in[7];
  const float* ar1 = (const float*)d_in[8];
  const float* Wo  = (const float*)d_in[9];
  const float* alo = (const float*)d_in[10];
  const float* aro = (const float*)d_in[11];
  const float* rWo = (const float*)d_in[12];
  const float* fcW = (const float*)d_in[13];

  float* out = (float*)d_out;
  float* out_logits = out;                 // [50000,40]
  float* out_h      = out + 2000000;       // [50000,256]
  float* out_seq    = out + 14800000;      // [50000,64]

  char* ws = (char*)d_ws;
  size_t o = 0;
  auto alc = [&](size_t bytes){ size_t r = o; o += (bytes + 255) & ~(size_t)255; return r; };
  size_t oXb   = alc((size_t)NN*256*2);
  size_t oFA   = alc((size_t)NN*256*2);
  size_t oFB   = alc((size_t)NN*256*2);
  size_t oEs   = alc((size_t)EPAD*4*4);
  size_t oSrcs = alc((size_t)EPAD*4);
  size_t oOff  = alc((size_t)(NN+1)*4);
  size_t oCnt  = alc((size_t)(NN+1)*4);
  size_t oCur  = alc((size_t)NN*4);
  size_t oPart = alc(64*4);
  size_t oEl   = alc((size_t)NN*4*4);
  size_t oEr   = alc((size_t)NN*4*4);
  size_t oRecs = alc((size_t)NN*4*4);
  size_t oReso = alc((size_t)NN*160*2);
  size_t oW0t  = alc(256*256*2);
  size_t oW1t  = alc(256*256*2);
  size_t oWct  = alc((size_t)384*256*2);
  size_t oFct  = alc((size_t)128*256*2);
  if (ws_size < o) return;

  u16* Xb   = (u16*)(ws + oXb);
  u16* fA   = (u16*)(ws + oFA);
  u16* fB   = (u16*)(ws + oFB);
  float* es = (float*)(ws + oEs);
  int* srcs = (int*)(ws + oSrcs);
  int* off  = (int*)(ws + oOff);
  int* cnt  = (int*)(ws + oCnt);
  int* cur  = (int*)(ws + oCur);
  int* part = (int*)(ws + oPart);
  float* el = (float*)(ws + oEl);
  float* er = (float*)(ws + oEr);
  float* recs = (float*)(ws + oRecs);
  u16* reso = (u16*)(ws + oReso);
  u16* W0t  = (u16*)(ws + oW0t);
  u16* W1t  = (u16*)(ws + oW1t);
  u16* Wct  = (u16*)(ws + oWct);
  u16* fct  = (u16*)(ws + oFct);

  // ---- converts (weights transposed for GEMM2 B-staging) ----
  k_f2b4<<<(NN*256/4 + 255)/256, 256, 0, stream>>>(inputs, Xb, NN*256/4);
  k_wtr<<<(256*256 + 255)/256, 256, 0, stream>>>(W0, W0t, 256);
  k_wtr<<<(256*256 + 255)/256, 256, 0, stream>>>(W1, W1t, 256);
  k_wtr<<<(256*64 + 255)/256, 256, 0, stream>>>(fcW, fct, 64);
  k_catWoT<<<(256*320 + 255)/256, 256, 0, stream>>>(rWo, Wo, Wct);

  // ---- CSR (padded; pad srcs -> 0, es pads zeroed by k_soft) ----
  hipMemsetAsync(cnt, 0, (size_t)(NN+1)*4, stream);
  k_count<<<(EE+255)/256, 256, 0, stream>>>(dst, cnt);
  const int NP1 = NN+1, NB = (NP1 + 1023)/1024;
  k_scan_blocks<<<NB, 256, 0, stream>>>(cnt, off, part, NP1);
  k_scan_part<<<1, 64, 0, stream>>>(part, NB);
  k_addback<<<NB, 256, 0, stream>>>(off, cur, part, NP1);
  k_scatter<<<(EE+255)/256, 256, 0, stream>>>(src, dst, cur, srcs);
  k_padfill<<<(NN+255)/256, 256, 0, stream>>>(off, cnt, srcs);

  const int GX = (NN + 127)/128;   // 391
  dim3 g256(GX, 2), g320(GX, 3), g64(GX, 1);

  // ---- seq_fts = X @ fc_W (f32 out) ----
  k_gemm2<64,0><<<g64, 256, 0, stream>>>(Xb, fct, out_seq, nullptr, nullptr, nullptr, nullptr, nullptr, NN, 64);

  // ---- layer 0: GEMM(+el/er) -> soft -> agg ----
  k_gemm2<128,1><<<g256, 256, 0, stream>>>(Xb, W0t, fA, nullptr, al0, ar0, el, er, NN, 256);
  k_soft<<<(NN*16 + 255)/256, 256, 0, stream>>>(el, er, srcs, off, cnt, es, recs);
  k_agg64<false><<<NN/4, 256, 0, stream>>>(fA, es, recs, off, srcs, nullptr, nullptr, fB);

  // ---- layer 1 ----
  k_gemm2<128,1><<<g256, 256, 0, stream>>>(fB, W1t, fA, nullptr, al1, ar1, el, er, NN, 256);
  k_soft<<<(NN*16 + 255)/256, 256, 0, stream>>>(el, er, srcs, off, cnt, es, recs);
  k_agg64<true><<<NN/4, 256, 0, stream>>>(fA, es, recs, off, srcs, fB, out_h, fB);

  // ---- output layer: fused [reso | Wo] GEMM -> eler -> soft -> agg ----
  k_gemm2<128,2><<<g320, 256, 0, stream>>>(fB, Wct, reso, fA, nullptr, nullptr, nullptr, nullptr, NN, 320);
  k_eler<<<(NN*64 + 255)/256, 256, 0, stream>>>(fA, alo, aro, el, er, 40, 160);
  k_soft<<<(NN*16 + 255)/256, 256, 0, stream>>>(el, er, srcs, off, cnt, es, recs);
  k_agg_out<<<NN/4, 256, 0, stream>>>(fA, es, recs, off, srcs, reso, out_logits);
}

// Round 9
// 468.556 us; speedup vs baseline: 1.1373x; 1.0509x over previous
//
#include <hip/hip_runtime.h>

typedef unsigned short u16;
typedef unsigned int u32;
typedef __attribute__((ext_vector_type(8))) short short8;
typedef __attribute__((ext_vector_type(4))) float f32x4;

#define NN 50000
#define EE 800000
#define EPAD (EE + 8*NN)   // max padded edges = 1,200,000

__device__ __forceinline__ float b2f(u16 u){ union{float f;u32 i;}x; x.i=((u32)u)<<16; return x.f; }
__device__ __forceinline__ u16 f2b(float f){ union{float f;u32 i;}x; x.f=f; u32 i=x.i; return (u16)((i + 0x7fffu + ((i>>16)&1u))>>16); }

// ---------- converts ----------
__global__ void k_f2b4(const float* __restrict__ x, u16* __restrict__ y, int n4){
  int i = blockIdx.x*256 + threadIdx.x;
  if (i >= n4) return;
  float4 v = ((const float4*)x)[i];
  ushort4 o; o.x=f2b(v.x); o.y=f2b(v.y); o.z=f2b(v.z); o.w=f2b(v.w);
  ((ushort4*)y)[i]=o;
}

// merged transpose-converts:
//  W0t[256][256], W1t[256][256], fct[64][256], Wct[200][256]
//  Wct row j<40: 0.25*sum_h rWo[k][h*40+j]  (head-mean fold); row 40..199: Wo[k][j-40]
__global__ void k_wcvt(const float* __restrict__ W0, const float* __restrict__ W1,
                       const float* __restrict__ fcW, const float* __restrict__ rWo,
                       const float* __restrict__ Wo,
                       u16* __restrict__ W0t, u16* __restrict__ W1t,
                       u16* __restrict__ fct, u16* __restrict__ Wct){
  int i = blockIdx.x*256 + threadIdx.x;
  if (i < 65536){
    int n = i >> 8, k = i & 255;
    W0t[i] = f2b(W0[k*256 + n]);
  } else if (i < 131072){
    int j = i - 65536; int n = j >> 8, k = j & 255;
    W1t[j] = f2b(W1[k*256 + n]);
  } else if (i < 147456){
    int j = i - 131072; int n = j >> 8, k = j & 255;
    fct[j] = f2b(fcW[k*64 + n]);
  } else if (i < 198656){
    int j = i - 147456; int r = j >> 8, k = j & 255;
    float v;
    if (r < 40) v = 0.25f*(rWo[k*160 + r] + rWo[k*160 + 40 + r] + rWo[k*160 + 80 + r] + rWo[k*160 + 120 + r]);
    else        v = Wo[k*160 + (r - 40)];
    Wct[j] = f2b(v);
  }
}

// ---------- CSR build (padded segments, atomic allocation) ----------
__global__ void k_count(const int* __restrict__ dst, int* __restrict__ cnt){
  int i = blockIdx.x*256+threadIdx.x; if (i<EE) atomicAdd(&cnt[dst[i]],1);
}

__global__ void k_alloc(const int* __restrict__ cnt, int* __restrict__ off, int* __restrict__ cur,
                        int* __restrict__ total){
  int n = blockIdx.x*256+threadIdx.x; if (n>=NN) return;
  int pc = (cnt[n]+7)&~7;
  int o = atomicAdd(total, pc);
  off[n]=o; cur[n]=o;
}

__global__ void k_scatter(const int* __restrict__ src, const int* __restrict__ dst, int* __restrict__ cur,
                          int* __restrict__ srcs){
  int i = blockIdx.x*256+threadIdx.x; if (i>=EE) return;
  int d = dst[i]; int p = atomicAdd(&cur[d],1);
  srcs[p]=src[i];
}

// fill pad slots with node 0 (es for pads is zeroed by k_soft -> 0 contribution)
__global__ void k_padfill(const int* __restrict__ off, const int* __restrict__ cnt, int* __restrict__ srcs){
  int n = blockIdx.x*256+threadIdx.x; if (n>=NN) return;
  int deg = cnt[n];
  int e = off[n]+deg, e1 = off[n]+((deg+7)&~7);
  for (; e<e1; ++e) srcs[e] = 0;
}

// ---------- GEMM2: C[M,:] = A[M,256](bf16) @ Bt[N,256]^T, f32 acc ----------
// BM=128, full-K LDS stage via global_load_lds (pre-swizzled source), 256 thr = 4 waves (2Mx2N)
// MODE 0: f32 out. MODE 1: bf16 out + fused el/er epilogue (64-dim heads).
// MODE 2: split: c<40 -> C0 (reso40 bf16 [n][40]), 40<=c<200 -> C1 (fA bf16 [n][160]).
template<int BN, int MODE>
__global__ __launch_bounds__(256) void k_gemm2(const u16* __restrict__ A, const u16* __restrict__ Bt,
                                               void* __restrict__ C0, void* __restrict__ C1,
                                               const float* __restrict__ AL, const float* __restrict__ AR,
                                               float* __restrict__ EL, float* __restrict__ ER,
                                               int M, int ldC){
  __shared__ u16 lds[(128+BN)*256];
  u16* As = lds;
  u16* Bs = lds + 128*256;
  const int tid = threadIdx.x;
  const int row0 = blockIdx.x * 128;
  const int n0   = blockIdx.y * BN;
  #pragma unroll
  for (int it=0; it<16; ++it){
    int slot = it*256 + tid;
    int r = slot >> 5, s = slot & 31;
    int gs = s ^ (r & 7);
    const u16* gp = A + (size_t)(row0 + r)*256 + (gs<<3);
    u16* lp = As + (size_t)(it*256 + (tid & ~63))*8;
    __builtin_amdgcn_global_load_lds((const void*)gp, (void*)lp, 16, 0, 0);
  }
  #pragma unroll
  for (int it=0; it<BN/8; ++it){
    int slot = it*256 + tid;
    int r = slot >> 5, s = slot & 31;
    int gs = s ^ (r & 7);
    const u16* gp = Bt + (size_t)(n0 + r)*256 + (gs<<3);
    u16* lp = Bs + (size_t)(it*256 + (tid & ~63))*8;
    __builtin_amdgcn_global_load_lds((const void*)gp, (void*)lp, 16, 0, 0);
  }
  __syncthreads();
  const int wave = tid >> 6, l = tid & 63;
  const int wm = wave >> 1, wn = wave & 1;
  const int lr = l & 15, lq = l >> 4;
  const int NR = BN/32;
  f32x4 acc[4][4];
  #pragma unroll
  for (int mr=0;mr<4;++mr)
    #pragma unroll
    for (int nr=0;nr<NR;++nr) acc[mr][nr]=(f32x4)0.0f;
  #pragma unroll
  for (int kk=0; kk<8; ++kk){
    short8 a[4], b[4];
    #pragma unroll
    for (int mr=0;mr<4;++mr){
      int rloc = wm*64 + mr*16 + lr;
      int byo = rloc*512 + ((kk*64 + lq*16) ^ ((rloc&7)<<4));
      a[mr] = *(const short8*)((const char*)As + byo);
    }
    #pragma unroll
    for (int nr=0;nr<NR;++nr){
      int cloc = wn*(BN/2) + nr*16 + lr;
      int byo = cloc*512 + ((kk*64 + lq*16) ^ ((cloc&7)<<4));
      b[nr] = *(const short8*)((const char*)Bs + byo);
    }
    #pragma unroll
    for (int mr=0;mr<4;++mr)
      #pragma unroll
      for (int nr=0;nr<NR;++nr)
        acc[mr][nr] = __builtin_amdgcn_mfma_f32_16x16x32_bf16(a[mr], b[nr], acc[mr][nr], 0, 0, 0);
  }
  #pragma unroll
  for (int mr=0;mr<4;++mr)
    #pragma unroll
    for (int nr=0;nr<NR;++nr)
      #pragma unroll
      for (int q=0;q<4;++q){
        int r = row0 + wm*64 + mr*16 + lq*4 + q;
        if (r < M){
          int c = n0 + wn*(BN/2) + nr*16 + lr;
          float v = acc[mr][nr][q];
          if constexpr (MODE == 0)      ((float*)C0)[(size_t)r*ldC + c] = v;
          else if constexpr (MODE == 1) ((u16*)C0)[(size_t)r*ldC + c] = f2b(v);
          else {
            if (c < 40)       ((u16*)C0)[(size_t)r*40 + c]        = f2b(v);
            else if (c < 200) ((u16*)C1)[(size_t)r*160 + (c-40)]  = f2b(v);
          }
        }
      }
  if constexpr (MODE == 1){
    // fused el/er: this wave's 64-col span is exactly one 64-dim head
    const int head = (n0 + wn*64) >> 6;
    float alc[4], arc[4];
    #pragma unroll
    for (int nr=0;nr<4;++nr){
      int c = n0 + wn*64 + nr*16 + lr;
      alc[nr] = AL[c]; arc[nr] = AR[c];
    }
    #pragma unroll
    for (int mr=0;mr<4;++mr)
      #pragma unroll
      for (int q=0;q<4;++q){
        float suml = acc[mr][0][q]*alc[0] + acc[mr][1][q]*alc[1] + acc[mr][2][q]*alc[2] + acc[mr][3][q]*alc[3];
        float sumr = acc[mr][0][q]*arc[0] + acc[mr][1][q]*arc[1] + acc[mr][2][q]*arc[2] + acc[mr][3][q]*arc[3];
        #pragma unroll
        for (int msk=1; msk<16; msk<<=1){ suml += __shfl_xor(suml,msk,64); sumr += __shfl_xor(sumr,msk,64); }
        int r = row0 + wm*64 + mr*16 + lq*4 + q;
        if (lr == 0 && r < M){ EL[r*4+head] = suml; ER[r*4+head] = sumr; }
      }
  }
}

// ---------- generic el/er (output layer: Dh=40, HD=160) ----------
__global__ void k_eler(const u16* __restrict__ feat, const float* __restrict__ al, const float* __restrict__ ar,
                       float* __restrict__ el, float* __restrict__ er, int Dh, int HD){
  int t = blockIdx.x*256 + threadIdx.x;
  int n = t >> 6; int l = t & 63;
  if (n >= NN) return;
  int h = l >> 4, s = l & 15;
  const u16* fr = feat + (size_t)n*HD + h*Dh;
  const float* alh = al + h*Dh; const float* arh = ar + h*Dh;
  float accl = 0.f, accr = 0.f;
  for (int d = s; d < Dh; d += 16){ float f = b2f(fr[d]); accl += f*alh[d]; accr += f*arh[d]; }
  #pragma unroll
  for (int m = 8; m >= 1; m >>= 1){ accl += __shfl_xor(accl, m, 64); accr += __shfl_xor(accr, m, 64); }
  if (s == 0){ el[n*4+h] = accl; er[n*4+h] = accr; }
}

// ---------- edge-parallel softmax, single pass (no max shift; scores bounded) ----------
__global__ void k_soft(const float* __restrict__ el, const float* __restrict__ er,
                       const int* __restrict__ srcs, const int* __restrict__ off, const int* __restrict__ cnt,
                       float* __restrict__ es, float* __restrict__ recs){
  int t = blockIdx.x*256 + threadIdx.x;
  int n = t >> 4; if (n >= NN) return;
  int g = t & 15;
  int o0 = off[n];
  int deg = cnt[n];
  int oend = o0 + deg, o1p = o0 + ((deg+7)&~7);
  float4 e4 = ((const float4*)er)[n];
  float4 s; s.x=s.y=s.z=s.w=0.f;
  for (int c = o0 + g; c < oend; c += 16){
    float4 a = ((const float4*)el)[srcs[c]];
    float4 v;
    v.x=a.x+e4.x; v.x = v.x>=0.f?v.x:0.2f*v.x; v.x=__expf(fminf(v.x,60.f));
    v.y=a.y+e4.y; v.y = v.y>=0.f?v.y:0.2f*v.y; v.y=__expf(fminf(v.y,60.f));
    v.z=a.z+e4.z; v.z = v.z>=0.f?v.z:0.2f*v.z; v.z=__expf(fminf(v.z,60.f));
    v.w=a.w+e4.w; v.w = v.w>=0.f?v.w:0.2f*v.w; v.w=__expf(fminf(v.w,60.f));
    ((float4*)es)[c]=v;
    s.x+=v.x; s.y+=v.y; s.z+=v.z; s.w+=v.w;
  }
  { int cp = oend + g; if (cp < o1p){ float4 z; z.x=z.y=z.z=z.w=0.f; ((float4*)es)[cp]=z; } }
  #pragma unroll
  for (int msk = 8; msk >= 1; msk >>= 1){
    s.x+=__shfl_xor(s.x,msk,64); s.y+=__shfl_xor(s.y,msk,64);
    s.z+=__shfl_xor(s.z,msk,64); s.w+=__shfl_xor(s.w,msk,64);
  }
  if (g == 0){
    float4 r;
    r.x = s.x>0.f ? 1.f/s.x : 0.f;
    r.y = s.y>0.f ? 1.f/s.y : 0.f;
    r.z = s.z>0.f ? 1.f/s.z : 0.f;
    r.w = s.w>0.f ? 1.f/s.w : 0.f;
    ((float4*)recs)[n] = r;
  }
}

// ---------- D=64 aggregation (R4-proven): wave per node, half-wave pairs, 8-edge unroll ----------
template<bool RES>
__global__ __launch_bounds__(256) void k_agg64(const u16* __restrict__ feat, const float* __restrict__ es,
    const float* __restrict__ recs, const int* __restrict__ off, const int* __restrict__ cnt,
    const int* __restrict__ srcs,
    const u16* __restrict__ resid, float* __restrict__ outf, u16* __restrict__ outb){
  const int l = threadIdx.x & 63, w = threadIdx.x >> 6;
  const int n = blockIdx.x*4 + w;
  const int o0 = off[n];
  const int o1p = o0 + ((cnt[n]+7)&~7);
  const int lh = l & 31;
  const int half = l >> 5;
  const int h = lh >> 3;
  float a0=0.f,a1=0.f,a2=0.f,a3=0.f,a4=0.f,a5=0.f,a6=0.f,a7=0.f;
  for (int i = o0; i < o1p; i += 8){
    #pragma unroll
    for (int u=0; u<4; ++u){
      int e = i + u*2 + half;
      int sv = srcs[e];
      float al = es[(size_t)e*4 + h];
      short8 f = *(const short8*)(feat + (size_t)sv*256 + lh*8);
      a0 += al*b2f((u16)f[0]); a1 += al*b2f((u16)f[1]);
      a2 += al*b2f((u16)f[2]); a3 += al*b2f((u16)f[3]);
      a4 += al*b2f((u16)f[4]); a5 += al*b2f((u16)f[5]);
      a6 += al*b2f((u16)f[6]); a7 += al*b2f((u16)f[7]);
    }
  }
  a0 += __shfl_xor(a0,32,64); a1 += __shfl_xor(a1,32,64);
  a2 += __shfl_xor(a2,32,64); a3 += __shfl_xor(a3,32,64);
  a4 += __shfl_xor(a4,32,64); a5 += __shfl_xor(a5,32,64);
  a6 += __shfl_xor(a6,32,64); a7 += __shfl_xor(a7,32,64);
  if (half == 0){
    float rc = recs[n*4+h];
    float v[8] = {a0*rc,a1*rc,a2*rc,a3*rc,a4*rc,a5*rc,a6*rc,a7*rc};
    if (RES){
      short8 r8 = *(const short8*)(resid + (size_t)n*256 + lh*8);
      #pragma unroll
      for (int j=0;j<8;++j) v[j] += b2f((u16)r8[j]);
    }
    #pragma unroll
    for (int j=0;j<8;++j) v[j] = v[j] > 0.f ? v[j] : expm1f(v[j]);
    if (outf){
      float4 q0; q0.x=v[0]; q0.y=v[1]; q0.z=v[2]; q0.w=v[3];
      float4 q1; q1.x=v[4]; q1.y=v[5]; q1.z=v[6]; q1.w=v[7];
      *(float4*)(outf + (size_t)n*256 + lh*8)     = q0;
      *(float4*)(outf + (size_t)n*256 + lh*8 + 4) = q1;
    }
    short8 ob;
    #pragma unroll
    for (int j=0;j<8;++j) ob[j] = (short)f2b(v[j]);
    *(short8*)(outb + (size_t)n*256 + lh*8) = ob;
  }
}

// ---------- output-layer aggregation: 8-edge groups, ushort8 loads, padded red, mean-folded reso ----------
__global__ __launch_bounds__(256) void k_agg_out(const u16* __restrict__ feat, const float* __restrict__ es,
    const float* __restrict__ recs, const int* __restrict__ off, const int* __restrict__ cnt,
    const int* __restrict__ srcs,
    const u16* __restrict__ reso40, float* __restrict__ logits){
  __shared__ float red[4][8][20][9];   // [..][9]: conflict-free stores
  __shared__ float fin[4][160];
  const int l = threadIdx.x & 63, w = threadIdx.x >> 6;
  const int n = blockIdx.x*4 + w;
  const int o0 = off[n];
  const int o1p = o0 + ((cnt[n]+7)&~7);
  const int s0 = l/20,        q0 = l%20;
  const int s1 = (64+l)/20,   q1 = (64+l)%20;
  const int s2 = (128+l)/20,  q2 = (128+l)%20;   // active l<32
  const int h0 = q0/5, h1 = q1/5, h2 = q2/5;
  float acc0[8], acc1[8], acc2[8];
  #pragma unroll
  for (int j=0;j<8;++j){ acc0[j]=0.f; acc1[j]=0.f; acc2[j]=0.f; }
  for (int i0 = o0; i0 < o1p; i0 += 8){
    {
      int e = i0 + s0; int sv = srcs[e]; float al = es[(size_t)e*4 + h0];
      short8 f = *(const short8*)(feat + (size_t)sv*160 + q0*8);
      #pragma unroll
      for (int j=0;j<8;++j) acc0[j] += al*b2f((u16)f[j]);
    }
    {
      int e = i0 + s1; int sv = srcs[e]; float al = es[(size_t)e*4 + h1];
      short8 f = *(const short8*)(feat + (size_t)sv*160 + q1*8);
      #pragma unroll
      for (int j=0;j<8;++j) acc1[j] += al*b2f((u16)f[j]);
    }
    if (l < 32){
      int e = i0 + s2; int sv = srcs[e]; float al = es[(size_t)e*4 + h2];
      short8 f = *(const short8*)(feat + (size_t)sv*160 + q2*8);
      #pragma unroll
      for (int j=0;j<8;++j) acc2[j] += al*b2f((u16)f[j]);
    }
  }
  #pragma unroll
  for (int j=0;j<8;++j) red[w][s0][q0][j] = acc0[j];
  #pragma unroll
  for (int j=0;j<8;++j) red[w][s1][q1][j] = acc1[j];
  if (l < 32){
    #pragma unroll
    for (int j=0;j<8;++j) red[w][s2][q2][j] = acc2[j];
  }
  __syncthreads();
  if (l < 20){
    const int q = l;
    float rc = 0.25f * recs[n*4 + q/5];
    #pragma unroll
    for (int j=0;j<8;++j){
      float v = red[w][0][q][j];
      #pragma unroll
      for (int s=1;s<8;++s) v += red[w][s][q][j];
      fin[w][q*8+j] = v*rc;
    }
  }
  __syncthreads();
  if (l < 40){
    float r = b2f(reso40[(size_t)n*40 + l]);
    logits[(size_t)n*40 + l] = fin[w][l]+fin[w][l+40]+fin[w][l+80]+fin[w][l+120] + r;
  }
}

extern "C" void kernel_launch(void* const* d_in, const int* in_sizes, int n_in,
                              void* d_out, int out_size, void* d_ws, size_t ws_size,
                              hipStream_t stream){
  const float* inputs = (const float*)d_in[0];
  const int*   src    = (const int*)d_in[1];
  const int*   dst    = (const int*)d_in[2];
  const float* W0  = (const float*)d_in[3];
  const float* al0 = (const float*)d_in[4];
  const float* ar0 = (const float*)d_in[5];
  const float* W1  = (const float*)d_in[6];
  const float* al1 = (const float*)d_in[7];
  const float* ar1 = (const float*)d_in[8];
  const float* Wo  = (const float*)d_in[9];
  const float* alo = (const float*)d_in[10];
  const float* aro = (const float*)d_in[11];
  const float* rWo = (const float*)d_in[12];
  const float* fcW = (const float*)d_in[13];

  float* out = (float*)d_out;
  float* out_logits = out;                 // [50000,40]
  float* out_h      = out + 2000000;       // [50000,256]
  float* out_seq    = out + 14800000;      // [50000,64]

  char* ws = (char*)d_ws;
  size_t o = 0;
  auto alc = [&](size_t bytes){ size_t r = o; o += (bytes + 255) & ~(size_t)255; return r; };
  size_t oXb   = alc((size_t)NN*256*2);
  size_t oFA   = alc((size_t)NN*256*2);
  size_t oFB   = alc((size_t)NN*256*2);
  size_t oEs   = alc((size_t)EPAD*4*4);
  size_t oSrcs = alc((size_t)EPAD*4);
  size_t oOff  = alc((size_t)NN*4);
  size_t oCnt  = alc((size_t)(NN+1)*4);   // cnt[NN] doubles as the atomic-alloc total (zeroed by memset)
  size_t oCur  = alc((size_t)NN*4);
  size_t oEl   = alc((size_t)NN*4*4);
  size_t oEr   = alc((size_t)NN*4*4);
  size_t oRecs = alc((size_t)NN*4*4);
  size_t oReso = alc((size_t)NN*40*2);
  size_t oW0t  = alc(256*256*2);
  size_t oW1t  = alc(256*256*2);
  size_t oWct  = alc((size_t)384*256*2);   // 200 valid rows + slack for staging overrun
  size_t oFct  = alc((size_t)128*256*2);   // 64 valid rows + slack
  if (ws_size < o) return;

  u16* Xb   = (u16*)(ws + oXb);
  u16* fA   = (u16*)(ws + oFA);
  u16* fB   = (u16*)(ws + oFB);
  float* es = (float*)(ws + oEs);
  int* srcs = (int*)(ws + oSrcs);
  int* off  = (int*)(ws + oOff);
  int* cnt  = (int*)(ws + oCnt);
  int* cur  = (int*)(ws + oCur);
  float* el = (float*)(ws + oEl);
  float* er = (float*)(ws + oEr);
  float* recs = (float*)(ws + oRecs);
  u16* reso40 = (u16*)(ws + oReso);
  u16* W0t  = (u16*)(ws + oW0t);
  u16* W1t  = (u16*)(ws + oW1t);
  u16* Wct  = (u16*)(ws + oWct);
  u16* fct  = (u16*)(ws + oFct);

  // ---- converts (merged) ----
  k_f2b4<<<(NN*256/4 + 255)/256, 256, 0, stream>>>(inputs, Xb, NN*256/4);
  k_wcvt<<<(198656 + 255)/256, 256, 0, stream>>>(W0, W1, fcW, rWo, Wo, W0t, W1t, fct, Wct);

  // ---- CSR (padded, atomic allocation) ----
  hipMemsetAsync(cnt, 0, (size_t)(NN+1)*4, stream);
  k_count<<<(EE+255)/256, 256, 0, stream>>>(dst, cnt);
  k_alloc<<<(NN+255)/256, 256, 0, stream>>>(cnt, off, cur, &cnt[NN]);
  k_scatter<<<(EE+255)/256, 256, 0, stream>>>(src, dst, cur, srcs);
  k_padfill<<<(NN+255)/256, 256, 0, stream>>>(off, cnt, srcs);

  const int GX = (NN + 127)/128;   // 391
  dim3 g256(GX, 2), g200(GX, 2), g64(GX, 1);

  // ---- seq_fts = X @ fc_W (f32 out) ----
  k_gemm2<64,0><<<g64, 256, 0, stream>>>(Xb, fct, out_seq, nullptr, nullptr, nullptr, nullptr, nullptr, NN, 64);

  // ---- layer 0: GEMM(+el/er) -> soft -> agg ----
  k_gemm2<128,1><<<g256, 256, 0, stream>>>(Xb, W0t, fA, nullptr, al0, ar0, el, er, NN, 256);
  k_soft<<<(NN*16 + 255)/256, 256, 0, stream>>>(el, er, srcs, off, cnt, es, recs);
  k_agg64<false><<<NN/4, 256, 0, stream>>>(fA, es, recs, off, cnt, srcs, nullptr, nullptr, fB);

  // ---- layer 1 ----
  k_gemm2<128,1><<<g256, 256, 0, stream>>>(fB, W1t, fA, nullptr, al1, ar1, el, er, NN, 256);
  k_soft<<<(NN*16 + 255)/256, 256, 0, stream>>>(el, er, srcs, off, cnt, es, recs);
  k_agg64<true><<<NN/4, 256, 0, stream>>>(fA, es, recs, off, cnt, srcs, fB, out_h, fB);

  // ---- output layer: fused [reso_mean | Wo] GEMM (200 cols) -> eler -> soft -> agg ----
  k_gemm2<128,2><<<g200, 256, 0, stream>>>(fB, Wct, reso40, fA, nullptr, nullptr, nullptr, nullptr, NN, 200);
  k_eler<<<(NN*64 + 255)/256, 256, 0, stream>>>(fA, alo, aro, el, er, 40, 160);
  k_soft<<<(NN*16 + 255)/256, 256, 0, stream>>>(el, er, srcs, off, cnt, es, recs);
  k_agg_out<<<NN/4, 256, 0, stream>>>(fA, es, recs, off, cnt, srcs, reso40, out_logits);
}

// Round 10
// 465.257 us; speedup vs baseline: 1.1453x; 1.0071x over previous
//
#include <hip/hip_runtime.h>

typedef unsigned short u16;
typedef unsigned int u32;
typedef __attribute__((ext_vector_type(8))) short short8;
typedef __attribute__((ext_vector_type(4))) float f32x4;

#define NN 50000
#define EE 800000
#define EPAD (EE + 8*NN)   // max padded edges; actual padded total <= EE+7*NN (>=50k slack)

__device__ __forceinline__ float b2f(u16 u){ union{float f;u32 i;}x; x.i=((u32)u)<<16; return x.f; }
__device__ __forceinline__ u16 f2b(float f){ union{float f;u32 i;}x; x.f=f; u32 i=x.i; return (u16)((i + 0x7fffu + ((i>>16)&1u))>>16); }

// ---------- merged converts: inputs (3.2M quads) + all weights ----------
__global__ void k_cvt_all(const float* __restrict__ inputs, u16* __restrict__ Xb,
                          const float* __restrict__ W0, const float* __restrict__ W1,
                          const float* __restrict__ fcW, const float* __restrict__ rWo,
                          const float* __restrict__ Wo,
                          u16* __restrict__ W0t, u16* __restrict__ W1t,
                          u16* __restrict__ fct, u16* __restrict__ Wct){
  int i = blockIdx.x*256 + threadIdx.x;
  if (i < 3200000){
    float4 v = ((const float4*)inputs)[i];
    ushort4 o; o.x=f2b(v.x); o.y=f2b(v.y); o.z=f2b(v.z); o.w=f2b(v.w);
    ((ushort4*)Xb)[i]=o;
    return;
  }
  int j = i - 3200000;
  if (j < 65536){
    int n = j >> 8, k = j & 255;
    W0t[j] = f2b(W0[k*256 + n]);
  } else if (j < 131072){
    int q = j - 65536; int n = q >> 8, k = q & 255;
    W1t[q] = f2b(W1[k*256 + n]);
  } else if (j < 147456){
    int q = j - 131072; int n = q >> 8, k = q & 255;
    fct[q] = f2b(fcW[k*64 + n]);
  } else if (j < 198656){
    int q = j - 147456; int r = q >> 8, k = q & 255;
    float v;
    if (r < 40) v = 0.25f*(rWo[k*160 + r] + rWo[k*160 + 40 + r] + rWo[k*160 + 80 + r] + rWo[k*160 + 120 + r]);
    else        v = Wo[k*160 + (r - 40)];
    Wct[q] = f2b(v);
  }
}

// ---------- CSR build (padded segments, atomic allocation) ----------
__global__ void k_count(const int* __restrict__ dst, int* __restrict__ cnt){
  int i = blockIdx.x*256+threadIdx.x; if (i<EE) atomicAdd(&cnt[dst[i]],1);
}

__global__ void k_alloc(const int* __restrict__ cnt, int* __restrict__ off, int* __restrict__ cur,
                        int* __restrict__ total){
  int n = blockIdx.x*256+threadIdx.x; if (n>=NN) return;
  int pc = (cnt[n]+7)&~7;
  int o = atomicAdd(total, pc);
  off[n]=o; cur[n]=o;
}

__global__ void k_scatter(const int* __restrict__ src, const int* __restrict__ dst, int* __restrict__ cur,
                          int* __restrict__ srcs){
  int i = blockIdx.x*256+threadIdx.x; if (i>=EE) return;
  int d = dst[i]; int p = atomicAdd(&cur[d],1);
  srcs[p]=src[i];
}

// fill pad slots with node 0 (es for pads zeroed by k_soft -> 0 contribution)
__global__ void k_padfill(const int* __restrict__ off, const int* __restrict__ cnt, int* __restrict__ srcs){
  int n = blockIdx.x*256+threadIdx.x; if (n>=NN) return;
  int deg = cnt[n];
  int e = off[n]+deg, e1 = off[n]+((deg+7)&~7);
  for (; e<e1; ++e) srcs[e] = 0;
}

// ---------- GEMM2: C[M,:] = A[M,256](bf16) @ Bt[N,256]^T, f32 acc ----------
// BM=128, full-K LDS stage via global_load_lds (pre-swizzled source), 256 thr = 4 waves (2Mx2N)
// MODE 0: f32 out. MODE 1: bf16 out + fused el/er epilogue (64-dim heads).
// MODE 2: split: c<40 -> C0 (reso40 bf16 [n][40]), 40<=c<200 -> C1 (fA bf16 [n][160]).
template<int BN, int MODE>
__global__ __launch_bounds__(256) void k_gemm2(const u16* __restrict__ A, const u16* __restrict__ Bt,
                                               void* __restrict__ C0, void* __restrict__ C1,
                                               const float* __restrict__ AL, const float* __restrict__ AR,
                                               float* __restrict__ EL, float* __restrict__ ER,
                                               int M, int ldC){
  __shared__ u16 lds[(128+BN)*256];
  u16* As = lds;
  u16* Bs = lds + 128*256;
  const int tid = threadIdx.x;
  const int row0 = blockIdx.x * 128;
  const int n0   = blockIdx.y * BN;
  #pragma unroll
  for (int it=0; it<16; ++it){
    int slot = it*256 + tid;
    int r = slot >> 5, s = slot & 31;
    int gs = s ^ (r & 7);
    const u16* gp = A + (size_t)(row0 + r)*256 + (gs<<3);
    u16* lp = As + (size_t)(it*256 + (tid & ~63))*8;
    __builtin_amdgcn_global_load_lds((const void*)gp, (void*)lp, 16, 0, 0);
  }
  #pragma unroll
  for (int it=0; it<BN/8; ++it){
    int slot = it*256 + tid;
    int r = slot >> 5, s = slot & 31;
    int gs = s ^ (r & 7);
    const u16* gp = Bt + (size_t)(n0 + r)*256 + (gs<<3);
    u16* lp = Bs + (size_t)(it*256 + (tid & ~63))*8;
    __builtin_amdgcn_global_load_lds((const void*)gp, (void*)lp, 16, 0, 0);
  }
  __syncthreads();
  const int wave = tid >> 6, l = tid & 63;
  const int wm = wave >> 1, wn = wave & 1;
  const int lr = l & 15, lq = l >> 4;
  const int NR = BN/32;
  f32x4 acc[4][4];
  #pragma unroll
  for (int mr=0;mr<4;++mr)
    #pragma unroll
    for (int nr=0;nr<NR;++nr) acc[mr][nr]=(f32x4)0.0f;
  #pragma unroll
  for (int kk=0; kk<8; ++kk){
    short8 a[4], b[4];
    #pragma unroll
    for (int mr=0;mr<4;++mr){
      int rloc = wm*64 + mr*16 + lr;
      int byo = rloc*512 + ((kk*64 + lq*16) ^ ((rloc&7)<<4));
      a[mr] = *(const short8*)((const char*)As + byo);
    }
    #pragma unroll
    for (int nr=0;nr<NR;++nr){
      int cloc = wn*(BN/2) + nr*16 + lr;
      int byo = cloc*512 + ((kk*64 + lq*16) ^ ((cloc&7)<<4));
      b[nr] = *(const short8*)((const char*)Bs + byo);
    }
    #pragma unroll
    for (int mr=0;mr<4;++mr)
      #pragma unroll
      for (int nr=0;nr<NR;++nr)
        acc[mr][nr] = __builtin_amdgcn_mfma_f32_16x16x32_bf16(a[mr], b[nr], acc[mr][nr], 0, 0, 0);
  }
  #pragma unroll
  for (int mr=0;mr<4;++mr)
    #pragma unroll
    for (int nr=0;nr<NR;++nr)
      #pragma unroll
      for (int q=0;q<4;++q){
        int r = row0 + wm*64 + mr*16 + lq*4 + q;
        if (r < M){
          int c = n0 + wn*(BN/2) + nr*16 + lr;
          float v = acc[mr][nr][q];
          if constexpr (MODE == 0)      ((float*)C0)[(size_t)r*ldC + c] = v;
          else if constexpr (MODE == 1) ((u16*)C0)[(size_t)r*ldC + c] = f2b(v);
          else {
            if (c < 40)       ((u16*)C0)[(size_t)r*40 + c]        = f2b(v);
            else if (c < 200) ((u16*)C1)[(size_t)r*160 + (c-40)]  = f2b(v);
          }
        }
      }
  if constexpr (MODE == 1){
    const int head = (n0 + wn*64) >> 6;
    float alc[4], arc[4];
    #pragma unroll
    for (int nr=0;nr<4;++nr){
      int c = n0 + wn*64 + nr*16 + lr;
      alc[nr] = AL[c]; arc[nr] = AR[c];
    }
    #pragma unroll
    for (int mr=0;mr<4;++mr)
      #pragma unroll
      for (int q=0;q<4;++q){
        float suml = acc[mr][0][q]*alc[0] + acc[mr][1][q]*alc[1] + acc[mr][2][q]*alc[2] + acc[mr][3][q]*alc[3];
        float sumr = acc[mr][0][q]*arc[0] + acc[mr][1][q]*arc[1] + acc[mr][2][q]*arc[2] + acc[mr][3][q]*arc[3];
        #pragma unroll
        for (int msk=1; msk<16; msk<<=1){ suml += __shfl_xor(suml,msk,64); sumr += __shfl_xor(sumr,msk,64); }
        int r = row0 + wm*64 + mr*16 + lq*4 + q;
        if (lr == 0 && r < M){ EL[r*4+head] = suml; ER[r*4+head] = sumr; }
      }
  }
}

// ---------- generic el/er (output layer: Dh=40, HD=160) ----------
__global__ void k_eler(const u16* __restrict__ feat, const float* __restrict__ al, const float* __restrict__ ar,
                       float* __restrict__ el, float* __restrict__ er, int Dh, int HD){
  int t = blockIdx.x*256 + threadIdx.x;
  int n = t >> 6; int l = t & 63;
  if (n >= NN) return;
  int h = l >> 4, s = l & 15;
  const u16* fr = feat + (size_t)n*HD + h*Dh;
  const float* alh = al + h*Dh; const float* arh = ar + h*Dh;
  float accl = 0.f, accr = 0.f;
  for (int d = s; d < Dh; d += 16){ float f = b2f(fr[d]); accl += f*alh[d]; accr += f*arh[d]; }
  #pragma unroll
  for (int m = 8; m >= 1; m >>= 1){ accl += __shfl_xor(accl, m, 64); accr += __shfl_xor(accr, m, 64); }
  if (s == 0){ el[n*4+h] = accl; er[n*4+h] = accr; }
}

// ---------- edge-parallel softmax, single pass, 8 lanes per node ----------
__global__ void k_soft(const float* __restrict__ el, const float* __restrict__ er,
                       const int* __restrict__ srcs, const int* __restrict__ off, const int* __restrict__ cnt,
                       float* __restrict__ es, float* __restrict__ recs){
  int t = blockIdx.x*256 + threadIdx.x;
  int n = t >> 3; if (n >= NN) return;
  int g = t & 7;
  int o0 = off[n];
  int deg = cnt[n];
  int oend = o0 + deg, o1p = o0 + ((deg+7)&~7);
  float4 e4 = ((const float4*)er)[n];
  float4 s; s.x=s.y=s.z=s.w=0.f;
  for (int c = o0 + g; c < oend; c += 8){
    float4 a = ((const float4*)el)[srcs[c]];
    float4 v;
    v.x=a.x+e4.x; v.x = v.x>=0.f?v.x:0.2f*v.x; v.x=__expf(fminf(v.x,60.f));
    v.y=a.y+e4.y; v.y = v.y>=0.f?v.y:0.2f*v.y; v.y=__expf(fminf(v.y,60.f));
    v.z=a.z+e4.z; v.z = v.z>=0.f?v.z:0.2f*v.z; v.z=__expf(fminf(v.z,60.f));
    v.w=a.w+e4.w; v.w = v.w>=0.f?v.w:0.2f*v.w; v.w=__expf(fminf(v.w,60.f));
    ((float4*)es)[c]=v;
    s.x+=v.x; s.y+=v.y; s.z+=v.z; s.w+=v.w;
  }
  { int cp = oend + g; if (cp < o1p){ float4 z; z.x=z.y=z.z=z.w=0.f; ((float4*)es)[cp]=z; } }
  #pragma unroll
  for (int msk = 4; msk >= 1; msk >>= 1){
    s.x+=__shfl_xor(s.x,msk,64); s.y+=__shfl_xor(s.y,msk,64);
    s.z+=__shfl_xor(s.z,msk,64); s.w+=__shfl_xor(s.w,msk,64);
  }
  if (g == 0){
    float4 r;
    r.x = s.x>0.f ? 1.f/s.x : 0.f;
    r.y = s.y>0.f ? 1.f/s.y : 0.f;
    r.z = s.z>0.f ? 1.f/s.z : 0.f;
    r.w = s.w>0.f ? 1.f/s.w : 0.f;
    ((float4*)recs)[n] = r;
  }
}

// ---------- D=64 aggregation: wave/node, half-wave pairs, 8-edge unroll, index prefetch ----------
template<bool RES>
__global__ __launch_bounds__(256) void k_agg64(const u16* __restrict__ feat, const float* __restrict__ es,
    const float* __restrict__ recs, const int* __restrict__ off, const int* __restrict__ cnt,
    const int* __restrict__ srcs,
    const u16* __restrict__ resid, float* __restrict__ outf, u16* __restrict__ outb){
  const int l = threadIdx.x & 63, w = threadIdx.x >> 6;
  const int n = blockIdx.x*4 + w;
  const int o0 = off[n];
  const int o1p = o0 + ((cnt[n]+7)&~7);
  const int lh = l & 31;
  const int half = l >> 5;
  const int h = lh >> 3;
  float a0=0.f,a1=0.f,a2=0.f,a3=0.f,a4=0.f,a5=0.f,a6=0.f,a7=0.f;
  // 2-stage pipeline: prefetch next block's (srcs, es) while gathering current feat rows.
  // Over-reads past o1p are safe: >=50k-edge slack in srcs/es; prefetched tail never used.
  int sv[4]; float ae[4];
  #pragma unroll
  for (int u=0;u<4;++u){
    int e = o0 + u*2 + half;
    sv[u] = srcs[e]; ae[u] = es[(size_t)e*4 + h];
  }
  for (int i = o0; i < o1p; i += 8){
    int sv2[4]; float ae2[4];
    #pragma unroll
    for (int u=0;u<4;++u){
      int e = i + 8 + u*2 + half;
      sv2[u] = srcs[e]; ae2[u] = es[(size_t)e*4 + h];
    }
    #pragma unroll
    for (int u=0; u<4; ++u){
      float al = ae[u];
      short8 f = *(const short8*)(feat + (size_t)sv[u]*256 + lh*8);
      a0 += al*b2f((u16)f[0]); a1 += al*b2f((u16)f[1]);
      a2 += al*b2f((u16)f[2]); a3 += al*b2f((u16)f[3]);
      a4 += al*b2f((u16)f[4]); a5 += al*b2f((u16)f[5]);
      a6 += al*b2f((u16)f[6]); a7 += al*b2f((u16)f[7]);
    }
    #pragma unroll
    for (int u=0;u<4;++u){ sv[u]=sv2[u]; ae[u]=ae2[u]; }
  }
  a0 += __shfl_xor(a0,32,64); a1 += __shfl_xor(a1,32,64);
  a2 += __shfl_xor(a2,32,64); a3 += __shfl_xor(a3,32,64);
  a4 += __shfl_xor(a4,32,64); a5 += __shfl_xor(a5,32,64);
  a6 += __shfl_xor(a6,32,64); a7 += __shfl_xor(a7,32,64);
  if (half == 0){
    float rc = recs[n*4+h];
    float v[8] = {a0*rc,a1*rc,a2*rc,a3*rc,a4*rc,a5*rc,a6*rc,a7*rc};
    if (RES){
      short8 r8 = *(const short8*)(resid + (size_t)n*256 + lh*8);
      #pragma unroll
      for (int j=0;j<8;++j) v[j] += b2f((u16)r8[j]);
    }
    #pragma unroll
    for (int j=0;j<8;++j) v[j] = v[j] > 0.f ? v[j] : expm1f(v[j]);
    if (outf){
      float4 q0; q0.x=v[0]; q0.y=v[1]; q0.z=v[2]; q0.w=v[3];
      float4 q1; q1.x=v[4]; q1.y=v[5]; q1.z=v[6]; q1.w=v[7];
      *(float4*)(outf + (size_t)n*256 + lh*8)     = q0;
      *(float4*)(outf + (size_t)n*256 + lh*8 + 4) = q1;
    }
    short8 ob;
    #pragma unroll
    for (int j=0;j<8;++j) ob[j] = (short)f2b(v[j]);
    *(short8*)(outb + (size_t)n*256 + lh*8) = ob;
  }
}

// ---------- output-layer aggregation: 8-edge groups, ushort8 loads, index prefetch ----------
__global__ __launch_bounds__(256) void k_agg_out(const u16* __restrict__ feat, const float* __restrict__ es,
    const float* __restrict__ recs, const int* __restrict__ off, const int* __restrict__ cnt,
    const int* __restrict__ srcs,
    const u16* __restrict__ reso40, float* __restrict__ logits){
  __shared__ float red[4][8][20][9];
  __shared__ float fin[4][160];
  const int l = threadIdx.x & 63, w = threadIdx.x >> 6;
  const int n = blockIdx.x*4 + w;
  const int o0 = off[n];
  const int o1p = o0 + ((cnt[n]+7)&~7);
  const int s0 = l/20,        q0 = l%20;
  const int s1 = (64+l)/20,   q1 = (64+l)%20;
  const int s2 = (128+l)/20,  q2 = (128+l)%20;   // active l<32
  const int h0 = q0/5, h1 = q1/5, h2 = q2/5;
  float acc0[8], acc1[8], acc2[8];
  #pragma unroll
  for (int j=0;j<8;++j){ acc0[j]=0.f; acc1[j]=0.f; acc2[j]=0.f; }
  int v0 = srcs[o0+s0], v1 = srcs[o0+s1], v2 = (l<32)? srcs[o0+s2] : 0;
  float b0 = es[(size_t)(o0+s0)*4+h0], b1 = es[(size_t)(o0+s1)*4+h1], b2 = (l<32)? es[(size_t)(o0+s2)*4+h2] : 0.f;
  for (int i0 = o0; i0 < o1p; i0 += 8){
    int nv0 = srcs[i0+8+s0], nv1 = srcs[i0+8+s1], nv2 = (l<32)? srcs[i0+8+s2] : 0;
    float nb0 = es[(size_t)(i0+8+s0)*4+h0], nb1 = es[(size_t)(i0+8+s1)*4+h1], nb2 = (l<32)? es[(size_t)(i0+8+s2)*4+h2] : 0.f;
    {
      short8 f = *(const short8*)(feat + (size_t)v0*160 + q0*8);
      #pragma unroll
      for (int j=0;j<8;++j) acc0[j] += b0*b2f((u16)f[j]);
    }
    {
      short8 f = *(const short8*)(feat + (size_t)v1*160 + q1*8);
      #pragma unroll
      for (int j=0;j<8;++j) acc1[j] += b1*b2f((u16)f[j]);
    }
    if (l < 32){
      short8 f = *(const short8*)(feat + (size_t)v2*160 + q2*8);
      #pragma unroll
      for (int j=0;j<8;++j) acc2[j] += b2*b2f((u16)f[j]);
    }
    v0=nv0; v1=nv1; v2=nv2; b0=nb0; b1=nb1; b2=nb2;
  }
  #pragma unroll
  for (int j=0;j<8;++j) red[w][s0][q0][j] = acc0[j];
  #pragma unroll
  for (int j=0;j<8;++j) red[w][s1][q1][j] = acc1[j];
  if (l < 32){
    #pragma unroll
    for (int j=0;j<8;++j) red[w][s2][q2][j] = acc2[j];
  }
  __syncthreads();
  if (l < 20){
    const int q = l;
    float rc = 0.25f * recs[n*4 + q/5];
    #pragma unroll
    for (int j=0;j<8;++j){
      float v = red[w][0][q][j];
      #pragma unroll
      for (int s=1;s<8;++s) v += red[w][s][q][j];
      fin[w][q*8+j] = v*rc;
    }
  }
  __syncthreads();
  if (l < 40){
    float r = b2f(reso40[(size_t)n*40 + l]);
    logits[(size_t)n*40 + l] = fin[w][l]+fin[w][l+40]+fin[w][l+80]+fin[w][l+120] + r;
  }
}

extern "C" void kernel_launch(void* const* d_in, const int* in_sizes, int n_in,
                              void* d_out, int out_size, void* d_ws, size_t ws_size,
                              hipStream_t stream){
  const float* inputs = (const float*)d_in[0];
  const int*   src    = (const int*)d_in[1];
  const int*   dst    = (const int*)d_in[2];
  const float* W0  = (const float*)d_in[3];
  const float* al0 = (const float*)d_in[4];
  const float* ar0 = (const float*)d_in[5];
  const float* W1  = (const float*)d_in[6];
  const float* al1 = (const float*)d_in[7];
  const float* ar1 = (const float*)d_in[8];
  const float* Wo  = (const float*)d_in[9];
  const float* alo = (const float*)d_in[10];
  const float* aro = (const float*)d_in[11];
  const float* rWo = (const float*)d_in[12];
  const float* fcW = (const float*)d_in[13];

  float* out = (float*)d_out;
  float* out_logits = out;                 // [50000,40]
  float* out_h      = out + 2000000;       // [50000,256]
  float* out_seq    = out + 14800000;      // [50000,64]

  char* ws = (char*)d_ws;
  size_t o = 0;
  auto alc = [&](size_t bytes){ size_t r = o; o += (bytes + 255) & ~(size_t)255; return r; };
  size_t oXb   = alc((size_t)NN*256*2);
  size_t oFA   = alc((size_t)NN*256*2);
  size_t oFB   = alc((size_t)NN*256*2);
  size_t oEs   = alc((size_t)EPAD*4*4);
  size_t oSrcs = alc((size_t)EPAD*4);
  size_t oOff  = alc((size_t)NN*4);
  size_t oCnt  = alc((size_t)(NN+1)*4);   // cnt[NN] doubles as atomic-alloc total
  size_t oCur  = alc((size_t)NN*4);
  size_t oEl   = alc((size_t)NN*4*4);
  size_t oEr   = alc((size_t)NN*4*4);
  size_t oRecs = alc((size_t)NN*4*4);
  size_t oReso = alc((size_t)NN*40*2);
  size_t oW0t  = alc(256*256*2);
  size_t oW1t  = alc(256*256*2);
  size_t oWct  = alc((size_t)384*256*2);
  size_t oFct  = alc((size_t)128*256*2);
  if (ws_size < o) return;

  u16* Xb   = (u16*)(ws + oXb);
  u16* fA   = (u16*)(ws + oFA);
  u16* fB   = (u16*)(ws + oFB);
  float* es = (float*)(ws + oEs);
  int* srcs = (int*)(ws + oSrcs);
  int* off  = (int*)(ws + oOff);
  int* cnt  = (int*)(ws + oCnt);
  int* cur  = (int*)(ws + oCur);
  float* el = (float*)(ws + oEl);
  float* er = (float*)(ws + oEr);
  float* recs = (float*)(ws + oRecs);
  u16* reso40 = (u16*)(ws + oReso);
  u16* W0t  = (u16*)(ws + oW0t);
  u16* W1t  = (u16*)(ws + oW1t);
  u16* Wct  = (u16*)(ws + oWct);
  u16* fct  = (u16*)(ws + oFct);

  // ---- converts (single kernel) ----
  k_cvt_all<<<(3200000 + 198656 + 255)/256, 256, 0, stream>>>(inputs, Xb, W0, W1, fcW, rWo, Wo,
                                                              W0t, W1t, fct, Wct);

  // ---- CSR (padded, atomic allocation) ----
  hipMemsetAsync(cnt, 0, (size_t)(NN+1)*4, stream);
  k_count<<<(EE+255)/256, 256, 0, stream>>>(dst, cnt);
  k_alloc<<<(NN+255)/256, 256, 0, stream>>>(cnt, off, cur, &cnt[NN]);
  k_scatter<<<(EE+255)/256, 256, 0, stream>>>(src, dst, cur, srcs);
  k_padfill<<<(NN+255)/256, 256, 0, stream>>>(off, cnt, srcs);

  const int GX = (NN + 127)/128;   // 391
  dim3 g256(GX, 2), g200(GX, 2), g64(GX, 1);

  // ---- seq_fts = X @ fc_W (f32 out) ----
  k_gemm2<64,0><<<g64, 256, 0, stream>>>(Xb, fct, out_seq, nullptr, nullptr, nullptr, nullptr, nullptr, NN, 64);

  // ---- layer 0: GEMM(+el/er) -> soft -> agg ----
  k_gemm2<128,1><<<g256, 256, 0, stream>>>(Xb, W0t, fA, nullptr, al0, ar0, el, er, NN, 256);
  k_soft<<<(NN*8 + 255)/256, 256, 0, stream>>>(el, er, srcs, off, cnt, es, recs);
  k_agg64<false><<<NN/4, 256, 0, stream>>>(fA, es, recs, off, cnt, srcs, nullptr, nullptr, fB);

  // ---- layer 1 ----
  k_gemm2<128,1><<<g256, 256, 0, stream>>>(fB, W1t, fA, nullptr, al1, ar1, el, er, NN, 256);
  k_soft<<<(NN*8 + 255)/256, 256, 0, stream>>>(el, er, srcs, off, cnt, es, recs);
  k_agg64<true><<<NN/4, 256, 0, stream>>>(fA, es, recs, off, cnt, srcs, fB, out_h, fB);

  // ---- output layer: fused [reso_mean | Wo] GEMM (200 cols) -> eler -> soft -> agg ----
  k_gemm2<128,2><<<g200, 256, 0, stream>>>(fB, Wct, reso40, fA, nullptr, nullptr, nullptr, nullptr, NN, 200);
  k_eler<<<(NN*64 + 255)/256, 256, 0, stream>>>(fA, alo, aro, el, er, 40, 160);
  k_soft<<<(NN*8 + 255)/256, 256, 0, stream>>>(el, er, srcs, off, cnt, es, recs);
  k_agg_out<<<NN/4, 256, 0, stream>>>(fA, es, recs, off, cnt, srcs, reso40, out_logits);
}